// Round 6
// baseline (667.329 us; speedup 1.0000x reference)
//
#include <hip/hip_runtime.h>

// ---------------------------------------------------------------------------
// SpatioTemporalBlock: biLSTM -> temporal MHA -> (collapsed) GAT -> fusion
// B=16 S=128 F=64 H=256 HEADS=4 DH=64 AH=128 D2=512
// FP32 inputs/outputs; MFMA operands converted f32->bf16 at staging.
// GAT collapses: broadcast node features => uniform alpha => dense layers.
//
// LSTM v7 = v5 (212us floor) + intra-XCD sync fastpath:
//   - grid 128, only bx&7 in {0,1} work (dir=bx&7, chunk=bx>>3). With the
//     empirical gfx950 round-robin bx%8->XCD map, all 16 WGs of a direction
//     share ONE XCD -> its L2 is a single physical cache for all of them.
//   - publish: sc1 agent atomic (device-scope guarantee, unchanged) PLUS a
//     plain global_store_dword (L2-resident copy for same-XCD readers).
//   - poll: rotation of 3 sc0 probes (L1-bypass, hits shared L2, ~250cyc RT)
//     and 1 sc1 probe (MALL, guarantees liveness if placement differs).
//     Correctness NEVER depends on co-location (G16-safe).
//   - one agent acquire fence (buffer_inv) per WG before the loop kills
//     cross-launch stale hbuf lines in XCD L2; MALL is memory-side so the
//     poison memset always wins there.
// Everything else byte-identical to v5: slab layout, coalesced tid*8 poll,
// h_s/x_s staging, z_s round-trip, per-thread gates, publish geometry,
// register-resident Whh/Wih.
// hbuf ring [128 steps][2 dir][16 b][256 c] bf16, memset 0xFF per launch;
// h never hits the NaN bit pattern (bounded by sigmoid*tanh).
// ---------------------------------------------------------------------------

typedef unsigned short u16;
typedef unsigned int u32;
typedef __bf16 bf16x8 __attribute__((ext_vector_type(8)));
typedef float f32x4 __attribute__((ext_vector_type(4)));
typedef unsigned short ushort8v __attribute__((ext_vector_type(8)));
typedef unsigned int uint4v __attribute__((ext_vector_type(4)));

#define BN_INV_F 0.9999950000374997f
#define POISON 0xFFFFFFFFu

__device__ __forceinline__ float b2f(u16 u) {
  union { float f; unsigned int i; } v;
  v.i = ((unsigned int)u) << 16;
  return v.f;
}
__device__ __forceinline__ u16 f2b(float f) {
  union { float f; unsigned int i; } v;
  v.f = f;
  unsigned int x = v.i;
  unsigned int r = (x + 0x7FFFu + ((x >> 16) & 1u)) >> 16;
  return (u16)r;
}
__device__ __forceinline__ f32x4 mfma16(ushort8v a, ushort8v b, f32x4 c) {
  return __builtin_amdgcn_mfma_f32_16x16x32_bf16(
      __builtin_bit_cast(bf16x8, a), __builtin_bit_cast(bf16x8, b), c, 0, 0, 0);
}
__device__ __forceinline__ float sigm(float x) { return 1.f / (1.f + __expf(-x)); }
__device__ __forceinline__ float tanh_f(float x) {
  float e = __expf(2.f * x);
  return 1.f - 2.f / (e + 1.f);
}
__device__ __forceinline__ bool ok8(const uint4v& a, const uint4v& b) {
  return (a.x != POISON) & (a.y != POISON) & (a.z != POISON) &
         (a.w != POISON) & (b.x != POISON) & (b.y != POISON) &
         (b.z != POISON) & (b.w != POISON);
}

// ---------------------------------------------------------------------------
// Kernel 1: bidirectional LSTM. grid = 128 blocks; workers: bx&7 in {0,1}
// (dir = bx&7, chunk q = bx>>3) -> 16 WGs per dir, co-XCD under round-robin
// placement. WG owns h-cols [q*16, q*16+16): 64 gate rows; wave w = gate w;
// per lane the B-row G = w*256 + q*16 + col16 (fragments in registers).
// Per step: issue x load -> poll h(t) (sc0 x3 / sc1 x1 rotation, coalesced
// tid*8 addressing) -> stage h_s/x_s -> barrier -> 10 MFMA -> z_s ->
// barrier -> per-thread gate math -> publish (sc1 atomic + plain L2 store).
// ---------------------------------------------------------------------------
__global__ __launch_bounds__(256) void lstm_kernel(
    const float* __restrict__ x,
    const float* __restrict__ Wih0, const float* __restrict__ Whh0,
    const float* __restrict__ bih0, const float* __restrict__ bhh0,
    const float* __restrict__ Wih1, const float* __restrict__ Whh1,
    const float* __restrict__ bih1, const float* __restrict__ bhh1,
    u32* __restrict__ hbuf,   // [128][2][16][128] u32 view (poisoned 0xFF)
    u16* __restrict__ tb)     // [16][128][512] bf16
{
  const int tid = threadIdx.x;
  const int bx = blockIdx.x;
  const int role = bx & 7;
  if (role > 1) return;           // 96 no-op WGs keep XCD mapping favorable
  const int d = role;
  const int q = bx >> 3;
  const float* Wih = d ? Wih1 : Wih0;
  const float* Whh = d ? Whh1 : Whh0;
  const float* bih = d ? bih1 : bih0;
  const float* bhh = d ? bhh1 : bhh0;

  const int w = tid >> 6;
  const int ln = tid & 63;
  const int col16 = ln & 15;
  const int quad = ln >> 4;

  __shared__ u16 h_s[16][264];
  __shared__ u16 x_s[16][72];
  __shared__ float z_s[4][16][17];
  __shared__ float bias_s[64];

  // ---- stage weights into registers (bf16 fragments), v1 row mapping ----
  const int G = w * 256 + q * 16 + col16;   // row w*16+col16 of this chunk
  ushort8v whh_f[8];
#pragma unroll
  for (int kt = 0; kt < 8; kt++) {
    const float4* src = (const float4*)(Whh + G * 256 + kt * 32 + quad * 8);
    float4 v0 = src[0], v1 = src[1];
    ushort8v t8;
    t8[0] = f2b(v0.x); t8[1] = f2b(v0.y); t8[2] = f2b(v0.z); t8[3] = f2b(v0.w);
    t8[4] = f2b(v1.x); t8[5] = f2b(v1.y); t8[6] = f2b(v1.z); t8[7] = f2b(v1.w);
    whh_f[kt] = t8;
  }
  ushort8v wih_f[2];
#pragma unroll
  for (int kt = 0; kt < 2; kt++) {
    const float4* src = (const float4*)(Wih + G * 64 + kt * 32 + quad * 8);
    float4 v0 = src[0], v1 = src[1];
    ushort8v t8;
    t8[0] = f2b(v0.x); t8[1] = f2b(v0.y); t8[2] = f2b(v0.z); t8[3] = f2b(v0.w);
    t8[4] = f2b(v1.x); t8[5] = f2b(v1.y); t8[6] = f2b(v1.z); t8[7] = f2b(v1.w);
    wih_f[kt] = t8;
  }
  if (tid < 64) {
    int grow = ((tid >> 4) << 8) + q * 16 + (tid & 15);
    bias_s[tid] = bih[grow] + bhh[grow];
  }

  // Invalidate stale agent-cache (XCD L2) lines from a previous launch so
  // sc0 probes can never observe pre-memset hbuf data. One-time cost.
  __builtin_amdgcn_fence(__ATOMIC_ACQUIRE, "agent");

  const int eb = tid >> 4;  // elementwise: batch
  const int ec = tid & 15;  // elementwise: h-col within chunk
  float c_reg = 0.f;

  for (int t = 0; t < 128; t++) {
    const int pos = d ? (127 - t) : t;

    // ---- issue x(pos) load (completion hidden under the poll) ----
    float4 xv = *(const float4*)(x + (eb * 128 + pos) * 64 + ec * 4);

    if (t > 0) {
      // ---- poll full h(t): coalesced tid*8 addressing; 3 sc0 probes
      //      (shared-L2 fast path) per 1 sc1 probe (MALL liveness) ----
      const u32* hw = hbuf + (t * 2 + d) * 2048 + tid * 8;
      uint4v a, b;
      for (;;) {
        asm volatile(
            "global_load_dwordx4 %0, %2, off sc0\n\t"
            "global_load_dwordx4 %1, %3, off sc0\n\t"
            "s_waitcnt vmcnt(0)"
            : "=v"(a), "=v"(b) : "v"(hw), "v"(hw + 4) : "memory");
        if (ok8(a, b)) break;
        asm volatile(
            "global_load_dwordx4 %0, %2, off sc0\n\t"
            "global_load_dwordx4 %1, %3, off sc0\n\t"
            "s_waitcnt vmcnt(0)"
            : "=v"(a), "=v"(b) : "v"(hw), "v"(hw + 4) : "memory");
        if (ok8(a, b)) break;
        asm volatile(
            "global_load_dwordx4 %0, %2, off sc0\n\t"
            "global_load_dwordx4 %1, %3, off sc0\n\t"
            "s_waitcnt vmcnt(0)"
            : "=v"(a), "=v"(b) : "v"(hw), "v"(hw + 4) : "memory");
        if (ok8(a, b)) break;
        asm volatile(
            "global_load_dwordx4 %0, %2, off sc1\n\t"
            "global_load_dwordx4 %1, %3, off sc1\n\t"
            "s_waitcnt vmcnt(0)"
            : "=v"(a), "=v"(b) : "v"(hw), "v"(hw + 4) : "memory");
        if (ok8(a, b)) break;
      }
      int b_ = tid >> 4, c0 = (tid & 15) * 16;
      *(u32*)&h_s[b_][c0 + 0] = a.x;
      *(u32*)&h_s[b_][c0 + 2] = a.y;
      *(u32*)&h_s[b_][c0 + 4] = a.z;
      *(u32*)&h_s[b_][c0 + 6] = a.w;
      *(u32*)&h_s[b_][c0 + 8] = b.x;
      *(u32*)&h_s[b_][c0 + 10] = b.y;
      *(u32*)&h_s[b_][c0 + 12] = b.z;
      *(u32*)&h_s[b_][c0 + 14] = b.w;
    }
    // stage x(pos) -> bf16 LDS (data already in flight / arrived)
    {
      int f0 = ec * 4;
      x_s[eb][f0 + 0] = f2b(xv.x);
      x_s[eb][f0 + 1] = f2b(xv.y);
      x_s[eb][f0 + 2] = f2b(xv.z);
      x_s[eb][f0 + 3] = f2b(xv.w);
    }
    __syncthreads();

    f32x4 acc = {0.f, 0.f, 0.f, 0.f};
#pragma unroll
    for (int kt = 0; kt < 2; kt++) {
      ushort8v av = *(const ushort8v*)&x_s[col16][kt * 32 + quad * 8];
      acc = mfma16(av, wih_f[kt], acc);
    }
    if (t > 0) {
#pragma unroll
      for (int kt = 0; kt < 8; kt++) {
        ushort8v av = *(const ushort8v*)&h_s[col16][kt * 32 + quad * 8];
        acc = mfma16(av, whh_f[kt], acc);
      }
    }
#pragma unroll
    for (int reg = 0; reg < 4; reg++)
      z_s[w][quad * 4 + reg][col16] = acc[reg];
    __syncthreads();

    // gates: torch order i, f, g, o (f32) — one element per thread
    float zi = z_s[0][eb][ec] + bias_s[ec];
    float zf = z_s[1][eb][ec] + bias_s[16 + ec];
    float zg = z_s[2][eb][ec] + bias_s[32 + ec];
    float zo = z_s[3][eb][ec] + bias_s[48 + ec];
    float si = sigm(zi), sf = sigm(zf), so = sigm(zo);
    float tg = tanh_f(zg);
    c_reg = sf * c_reg + si * tg;
    float hv = so * tanh_f(c_reg);
    u32 my = (u32)f2b(hv);
    u32 hi = __shfl_down((int)my, 1);  // partner col (ec+1), same wave
    if ((ec & 1) == 0) {
      u32 word = my | (hi << 16);
      *(u32*)&tb[(eb * 128 + pos) * 512 + d * 256 + q * 16 + ec] = word;
      if (t < 127) {
        u32* dst = hbuf + ((t + 1) * 2 + d) * 2048 + eb * 128 + (q * 16 + ec) / 2;
        // device-scope copy (MALL) first, then plain L2-resident copy for the
        // same-XCD sc0 fast path (ordered after, so an sc1 write-around can't
        // evict it). Same value both ways -> any interleaving is safe.
        __hip_atomic_store(dst, word, __ATOMIC_RELAXED,
                           __HIP_MEMORY_SCOPE_AGENT);
        asm volatile("global_store_dword %0, %1, off"
                     : : "v"(dst), "v"(word) : "memory");
      }
    }
    // no extra barrier: next-iter writes touch x_s/h_s only, whose reads all
    // completed before the z_s barrier above.
  }
}

// ---------------------------------------------------------------------------
// Kernel 2: QKV projection.  out = t @ W^T + bias, M=2048 N=512 K=512.
// grid = (32 Mtiles, 8 Ntiles, 3 which). Q,K,V stored bf16.
// ---------------------------------------------------------------------------
__global__ __launch_bounds__(256) void qkv_kernel(
    const u16* __restrict__ tb,
    const float* __restrict__ Wq, const float* __restrict__ bq,
    const float* __restrict__ Wk, const float* __restrict__ bk,
    const float* __restrict__ Wv, const float* __restrict__ bv,
    u16* __restrict__ Qb, u16* __restrict__ Kb, u16* __restrict__ Vb)
{
  const int tid = threadIdx.x;
  const int bxm = blockIdx.x, byn = blockIdx.y, bz = blockIdx.z;
  const float* W = (bz == 0) ? Wq : ((bz == 1) ? Wk : Wv);
  const float* bias = (bz == 0) ? bq : ((bz == 1) ? bk : bv);
  u16* outp = (bz == 0) ? Qb : ((bz == 1) ? Kb : Vb);

  __shared__ u16 a_s[64][40];
  __shared__ u16 b_s[64][40];
  const int w = tid >> 6, ln = tid & 63, col16 = ln & 15, quad = ln >> 4;

  f32x4 acc[4];
#pragma unroll
  for (int n = 0; n < 4; n++) acc[n] = (f32x4){0.f, 0.f, 0.f, 0.f};

  for (int kt = 0; kt < 16; kt++) {
    int r = tid >> 2, seg = tid & 3;
    *(ushort8v*)&a_s[r][seg * 8] =
        *(const ushort8v*)(tb + (bxm * 64 + r) * 512 + kt * 32 + seg * 8);
    const float4* wsrc = (const float4*)(W + (byn * 64 + r) * 512 + kt * 32 + seg * 8);
    float4 w0 = wsrc[0], w1 = wsrc[1];
    b_s[r][seg * 8 + 0] = f2b(w0.x);
    b_s[r][seg * 8 + 1] = f2b(w0.y);
    b_s[r][seg * 8 + 2] = f2b(w0.z);
    b_s[r][seg * 8 + 3] = f2b(w0.w);
    b_s[r][seg * 8 + 4] = f2b(w1.x);
    b_s[r][seg * 8 + 5] = f2b(w1.y);
    b_s[r][seg * 8 + 6] = f2b(w1.z);
    b_s[r][seg * 8 + 7] = f2b(w1.w);
    __syncthreads();
    ushort8v av = *(const ushort8v*)&a_s[w * 16 + col16][quad * 8];
#pragma unroll
    for (int n = 0; n < 4; n++) {
      ushort8v bvv = *(const ushort8v*)&b_s[n * 16 + col16][quad * 8];
      acc[n] = mfma16(av, bvv, acc[n]);
    }
    __syncthreads();
  }
#pragma unroll
  for (int n = 0; n < 4; n++) {
    float bs = bias[byn * 64 + n * 16 + col16];
#pragma unroll
    for (int reg = 0; reg < 4; reg++) {
      int row = bxm * 64 + w * 16 + quad * 4 + reg;
      outp[row * 512 + byn * 64 + n * 16 + col16] = f2b(acc[n][reg] + bs);
    }
  }
}

// ---------------------------------------------------------------------------
// Kernel 3: scores + softmax -> attn (d_out, f32). grid = (16 b, 4 h, 2 qhalf).
// Epilogue: per-row inv staged in LDS, cooperative coalesced float4 stores.
// ---------------------------------------------------------------------------
__global__ __launch_bounds__(256) void attn_kernel(
    const u16* __restrict__ Qb, const u16* __restrict__ Kb,
    float* __restrict__ attn_out)
{
  const int b = blockIdx.x, h = blockIdx.y, half = blockIdx.z;
  const int tid = threadIdx.x;
  __shared__ __align__(16) char smem[52224];
  __shared__ float inv_s[64];
  u16 (*q_s)[136] = (u16(*)[136])smem;
  u16 (*k_s)[136] = (u16(*)[136])(smem + 17408);
  float (*sc)[132] = (float(*)[132])smem;  // reused after MFMA

  const int w = tid >> 6, ln = tid & 63, col16 = ln & 15, quad = ln >> 4;
  {
    int r = tid >> 2, seg = tid & 3;
    const u16* src = Qb + (b * 128 + half * 64 + r) * 512 + h * 128 + seg * 32;
#pragma unroll
    for (int i = 0; i < 4; i++)
      *(ushort8v*)&q_s[r][seg * 32 + i * 8] = *(const ushort8v*)(src + i * 8);
    int r2 = tid >> 1, sg = tid & 1;
    const u16* src2 = Kb + (b * 128 + r2) * 512 + h * 128 + sg * 64;
#pragma unroll
    for (int i = 0; i < 8; i++)
      *(ushort8v*)&k_s[r2][sg * 64 + i * 8] = *(const ushort8v*)(src2 + i * 8);
  }
  __syncthreads();

  f32x4 acc[8];
#pragma unroll
  for (int n = 0; n < 8; n++) acc[n] = (f32x4){0.f, 0.f, 0.f, 0.f};
#pragma unroll
  for (int kd = 0; kd < 4; kd++) {
    ushort8v av = *(const ushort8v*)&q_s[w * 16 + col16][kd * 32 + quad * 8];
#pragma unroll
    for (int n = 0; n < 8; n++) {
      ushort8v bvv = *(const ushort8v*)&k_s[n * 16 + col16][kd * 32 + quad * 8];
      acc[n] = mfma16(av, bvv, acc[n]);
    }
  }
  __syncthreads();  // done with q_s/k_s before overwriting with sc
  const float scale = 0.08838834764831845f;  // 1/sqrt(128)
#pragma unroll
  for (int n = 0; n < 8; n++)
#pragma unroll
    for (int reg = 0; reg < 4; reg++)
      sc[w * 16 + quad * 4 + reg][n * 16 + col16] = acc[n][reg] * scale;
  __syncthreads();

  const int row = tid >> 2, p = tid & 3;
  float m = -1e30f;
  for (int c0 = 0; c0 < 32; c0++) m = fmaxf(m, sc[row][p * 32 + c0]);
  m = fmaxf(m, __shfl_xor(m, 1));
  m = fmaxf(m, __shfl_xor(m, 2));
  float s = 0.f;
  for (int c0 = 0; c0 < 32; c0++) {
    float e = __expf(sc[row][p * 32 + c0] - m);
    sc[row][p * 32 + c0] = e;
    s += e;
  }
  s += __shfl_xor(s, 1);
  s += __shfl_xor(s, 2);
  if (p == 0) inv_s[row] = 1.f / s;
  __syncthreads();

  // cooperative coalesced store: 64 rows x 128 f32
  float* obase = attn_out + (size_t)((b * 4 + h) * 128 + half * 64) * 128;
#pragma unroll
  for (int it = 0; it < 8; it++) {
    int idx = tid + it * 256;     // 0..2047
    int r = idx >> 5;             // row 0..63
    int c4 = idx & 31;            // float4 index 0..31
    float4 ev = *(float4*)&sc[r][c4 * 4];
    float iv = inv_s[r];
    float4 ov = {ev.x * iv, ev.y * iv, ev.z * iv, ev.w * iv};
    *(float4*)&obase[r * 128 + c4 * 4] = ov;
  }
}

// ---------------------------------------------------------------------------
// Kernel 4 (merged aolast+fuse): ao (q=127 only), last = ao@Wo^T+bo,
// collapsed GAT (2 dense layers), fusion Linear + LayerNorm + ReLU.
// grid = 16 (batch), 256 threads.
// ---------------------------------------------------------------------------
__global__ __launch_bounds__(256) void tail_kernel(
    const float* __restrict__ attn, const u16* __restrict__ Vb,
    const float* __restrict__ Wo, const float* __restrict__ bo,
    const float* __restrict__ W1, const float* __restrict__ b1,
    const float* __restrict__ g1, const float* __restrict__ be1,
    const float* __restrict__ W2, const float* __restrict__ pb2,
    const float* __restrict__ g2, const float* __restrict__ be2,
    const float* __restrict__ Wf, const float* __restrict__ bfv,
    const float* __restrict__ ln_g, const float* __restrict__ ln_b,
    float* __restrict__ dout)
{
  const int b = blockIdx.x, tid = threadIdx.x;
  __shared__ float arow[4][128];
  __shared__ float ao_s[512];
  __shared__ float last_s[512];
  __shared__ float h_s2[256];
  __shared__ float red_s[4];

  // ---- ao row (q=127) ----
#pragma unroll
  for (int e = 0; e < 2; e++) {
    int idx = tid + e * 256;
    int h = idx >> 7, k = idx & 127;
    arow[h][k] = attn[((b * 4 + h) * 128 + 127) * 128 + k];
  }
  __syncthreads();
#pragma unroll
  for (int pass = 0; pass < 2; pass++) {
    int d2 = tid + pass * 256;
    int hh = d2 >> 7;
    float acc = 0.f;
    for (int k = 0; k < 128; k++)
      acc += arow[hh][k] * b2f(Vb[(b * 128 + k) * 512 + d2]);
    ao_s[d2] = acc;
  }
  __syncthreads();
  // ---- last = ao @ Wo^T + bo ----
#pragma unroll
  for (int pass = 0; pass < 2; pass++) {
    int j = tid + pass * 256;
    float acc = bo[j];
    const float4* Wo4 = (const float4*)(Wo + j * 512);
    for (int k4 = 0; k4 < 128; k4++) {
      float4 wv = Wo4[k4];
      acc += ao_s[k4 * 4 + 0] * wv.x + ao_s[k4 * 4 + 1] * wv.y +
             ao_s[k4 * 4 + 2] * wv.z + ao_s[k4 * 4 + 3] * wv.w;
    }
    last_s[j] = acc;
  }
  __syncthreads();

  // ---- collapsed GAT layer 1 ----
  const int j = tid;
  float acc = 0.f;
  for (int k = 0; k < 512; k++) acc += last_s[k] * W1[k * 256 + j];
  float u = (acc + b1[j]) * BN_INV_F * g1[j] + be1[j];
  float h1 = u > 0.f ? u : expm1f(u);
  h_s2[j] = h1;
  __syncthreads();

  // ---- collapsed GAT layer 2 ----
  float acc2 = 0.f;
  for (int k = 0; k < 256; k++) acc2 += h_s2[k] * W2[k * 256 + j];
  float u2 = (acc2 + pb2[j]) * BN_INV_F * g2[j] + be2[j];
  float sp = u2 > 0.f ? u2 : expm1f(u2);
  __syncthreads();
  h_s2[j] = sp;
  __syncthreads();

  // ---- fusion Linear ----
  float f = bfv[j];
  const float4* Wf4 = (const float4*)(Wf + j * 768);
  for (int k4 = 0; k4 < 128; k4++) {
    float4 wv = Wf4[k4];
    f += last_s[k4 * 4 + 0] * wv.x + last_s[k4 * 4 + 1] * wv.y +
         last_s[k4 * 4 + 2] * wv.z + last_s[k4 * 4 + 3] * wv.w;
  }
  for (int k4 = 0; k4 < 64; k4++) {
    float4 wv = Wf4[128 + k4];
    f += h_s2[k4 * 4 + 0] * wv.x + h_s2[k4 * 4 + 1] * wv.y +
         h_s2[k4 * 4 + 2] * wv.z + h_s2[k4 * 4 + 3] * wv.w;
  }

  // ---- LayerNorm + ReLU ----
  float v = f;
#pragma unroll
  for (int o = 32; o > 0; o >>= 1) v += __shfl_xor(v, o);
  if ((tid & 63) == 0) red_s[tid >> 6] = v;
  __syncthreads();
  float mu = (red_s[0] + red_s[1] + red_s[2] + red_s[3]) * (1.f / 256.f);
  float dv = f - mu;
  float vv = dv * dv;
#pragma unroll
  for (int o = 32; o > 0; o >>= 1) vv += __shfl_xor(vv, o);
  __syncthreads();
  if ((tid & 63) == 0) red_s[tid >> 6] = vv;
  __syncthreads();
  float var = (red_s[0] + red_s[1] + red_s[2] + red_s[3]) * (1.f / 256.f);
  float y = dv * rsqrtf(var + 1e-5f) * ln_g[j] + ln_b[j];
  dout[b * 256 + j] = fmaxf(y, 0.f);
}

// ---------------------------------------------------------------------------
// ws layout (bytes):
//   0         hbuf  [128][2][16][256] bf16  2097152  (memset 0xFF each call)
//   2129920   tb    [16][128][512] bf16     2097152
//   4227072   Q     [2048][512] bf16        2097152
//   6324224   K     [2048][512] bf16        2097152
//   8421376   V     [2048][512] bf16        2097152  -> total 10518528 bytes
// ---------------------------------------------------------------------------
extern "C" void kernel_launch(void* const* d_in, const int* in_sizes, int n_in,
                              void* d_out, int out_size, void* d_ws, size_t ws_size,
                              hipStream_t stream) {
  (void)in_sizes; (void)n_in; (void)out_size; (void)ws_size;
  const float* x     = (const float*)d_in[0];
  const float* Wih_f = (const float*)d_in[2];
  const float* Whh_f = (const float*)d_in[3];
  const float* bih_f = (const float*)d_in[4];
  const float* bhh_f = (const float*)d_in[5];
  const float* Wih_b = (const float*)d_in[6];
  const float* Whh_b = (const float*)d_in[7];
  const float* bih_b = (const float*)d_in[8];
  const float* bhh_b = (const float*)d_in[9];
  const float* Wq = (const float*)d_in[10]; const float* bq = (const float*)d_in[11];
  const float* Wk = (const float*)d_in[12]; const float* bk = (const float*)d_in[13];
  const float* Wv = (const float*)d_in[14]; const float* bv = (const float*)d_in[15];
  const float* Wo = (const float*)d_in[16]; const float* bo = (const float*)d_in[17];
  const float* W1 = (const float*)d_in[18];
  const float* b1 = (const float*)d_in[21];
  const float* g1 = (const float*)d_in[22]; const float* be1 = (const float*)d_in[23];
  const float* W2 = (const float*)d_in[24];
  const float* pb2 = (const float*)d_in[27];
  const float* g2 = (const float*)d_in[28]; const float* be2 = (const float*)d_in[29];
  const float* Wf = (const float*)d_in[30]; const float* bfv = (const float*)d_in[31];
  const float* ln_g = (const float*)d_in[32]; const float* ln_b = (const float*)d_in[33];

  float* dout = (float*)d_out;
  char* ws = (char*)d_ws;
  u32* hbuf = (u32*)(ws + 0);
  u16* tb   = (u16*)(ws + 2129920);
  u16* Qb   = (u16*)(ws + 4227072);
  u16* Kb   = (u16*)(ws + 6324224);
  u16* Vb   = (u16*)(ws + 8421376);

  (void)hipMemsetAsync(ws, 0xFF, 2097152, stream);  // poison hbuf ring
  lstm_kernel<<<128, 256, 0, stream>>>(x, Wih_f, Whh_f, bih_f, bhh_f,
                                       Wih_b, Whh_b, bih_b, bhh_b,
                                       hbuf, tb);
  qkv_kernel<<<dim3(32, 8, 3), 256, 0, stream>>>(tb, Wq, bq, Wk, bk, Wv, bv,
                                                 Qb, Kb, Vb);
  attn_kernel<<<dim3(16, 4, 2), 256, 0, stream>>>(Qb, Kb, dout + 4096);
  tail_kernel<<<16, 256, 0, stream>>>(dout + 4096, Vb, Wo, bo,
                                      W1, b1, g1, be1, W2, pb2, g2, be2,
                                      Wf, bfv, ln_g, ln_b, dout);
}

// Round 8
// 631.804 us; speedup vs baseline: 1.0562x; 1.0562x over previous
//
#include <hip/hip_runtime.h>

// ---------------------------------------------------------------------------
// SpatioTemporalBlock: biLSTM -> temporal MHA -> (collapsed) GAT -> fusion
// B=16 S=128 F=64 H=256 HEADS=4 DH=64 AH=128 D2=512
// FP32 inputs/outputs; MFMA operands converted f32->bf16 at staging.
// GAT collapses: broadcast node features => uniform alpha => dense layers.
//
// LSTM v8: 2-party sync. grid = 4 WGs x 512 threads: d = bx&1, p = bx>>1.
// WG (d,p) owns h-cols [p*128, p*128+128) (512 gate rows).
//   - 8 waves; wave w: gate g=w>>1, col-sub s=w&1, 4 n-tiles of 16 cols.
//     B-fragments (Whh 128 VGPR + Wih 32 VGPR) register-resident.
//   - Per step: own 128 cols are computed and written to LDS h_s locally
//     (no fabric RT); only the OTHER WG's 128 cols (4KB) cross the proven
//     sc1 poison fabric. Publishers per direction: 2 (was 16) -> jitter
//     and poll traffic collapse.
//   - Poll: coalesced dwordx2/lane sc1; publish: relaxed agent atomic u32,
//     64B-contiguous chunks per batch, hbuf store BEFORE tb store.
// Protocol invariants unchanged from the verified v5: slab layout
// [128 t][2 d][16 b][128 u32], memset 0xFF per launch, sc1 loads, h never
// hits the NaN bit pattern (bounded by sigmoid*tanh).
// (Resubmission of round-6 source: the bench failed with a container-level
// error and the protocol audit found no deadlock; identical source keeps
// the infra-vs-kernel A/B clean.)
// ---------------------------------------------------------------------------

typedef unsigned short u16;
typedef unsigned int u32;
typedef __bf16 bf16x8 __attribute__((ext_vector_type(8)));
typedef float f32x4 __attribute__((ext_vector_type(4)));
typedef unsigned short ushort8v __attribute__((ext_vector_type(8)));
typedef unsigned int uint2v __attribute__((ext_vector_type(2)));

#define BN_INV_F 0.9999950000374997f
#define POISON 0xFFFFFFFFu

__device__ __forceinline__ float b2f(u16 u) {
  union { float f; unsigned int i; } v;
  v.i = ((unsigned int)u) << 16;
  return v.f;
}
__device__ __forceinline__ u16 f2b(float f) {
  union { float f; unsigned int i; } v;
  v.f = f;
  unsigned int x = v.i;
  unsigned int r = (x + 0x7FFFu + ((x >> 16) & 1u)) >> 16;
  return (u16)r;
}
__device__ __forceinline__ f32x4 mfma16(ushort8v a, ushort8v b, f32x4 c) {
  return __builtin_amdgcn_mfma_f32_16x16x32_bf16(
      __builtin_bit_cast(bf16x8, a), __builtin_bit_cast(bf16x8, b), c, 0, 0, 0);
}
__device__ __forceinline__ float sigm(float x) { return 1.f / (1.f + __expf(-x)); }
__device__ __forceinline__ float tanh_f(float x) {
  float e = __expf(2.f * x);
  return 1.f - 2.f / (e + 1.f);
}

// ---------------------------------------------------------------------------
// Kernel 1: bidirectional LSTM, 2-party sync (see header).
// ---------------------------------------------------------------------------
__global__ __launch_bounds__(512) void lstm_kernel(
    const float* __restrict__ x,
    const float* __restrict__ Wih0, const float* __restrict__ Whh0,
    const float* __restrict__ bih0, const float* __restrict__ bhh0,
    const float* __restrict__ Wih1, const float* __restrict__ Whh1,
    const float* __restrict__ bih1, const float* __restrict__ bhh1,
    u32* __restrict__ hbuf,   // [128][2][16][128] u32 view (poisoned 0xFF)
    u16* __restrict__ tb)     // [16][128][512] bf16
{
  const int tid = threadIdx.x;
  const int bx = blockIdx.x;
  const int d = bx & 1;
  const int p = bx >> 1;          // col-half owner: cols [p*128, p*128+128)
  const int op = 1 - p;
  const float* Wih = d ? Wih1 : Wih0;
  const float* Whh = d ? Whh1 : Whh0;
  const float* bih = d ? bih1 : bih0;
  const float* bhh = d ? bhh1 : bhh0;

  const int w = tid >> 6;          // wave 0..7
  const int ln = tid & 63;
  const int col16 = ln & 15;
  const int quad = ln >> 4;
  const int g = w >> 1;            // gate 0..3
  const int s = w & 1;             // 64-col sub-half within our 128

  __shared__ u16 h_s[16][264];     // full 256 cols (both halves)
  __shared__ u16 x_s[16][72];
  __shared__ float z_s[4][16][132];
  __shared__ float bias_s[4][128];

  // ---- stage weights into registers (bf16 fragments) ----
  // wave w, n-tile nt, lane (quad,col16): row G = g*256 + p*128 + s*64 +
  // nt*16 + col16; K-frag kt covers cols kt*32 + quad*8 .. +7.
  ushort8v whh_f[4][8];
  ushort8v wih_f[4][2];
#pragma unroll
  for (int nt = 0; nt < 4; nt++) {
    const int G = g * 256 + p * 128 + s * 64 + nt * 16 + col16;
#pragma unroll
    for (int kt = 0; kt < 8; kt++) {
      const float4* src = (const float4*)(Whh + G * 256 + kt * 32 + quad * 8);
      float4 v0 = src[0], v1 = src[1];
      ushort8v t8;
      t8[0] = f2b(v0.x); t8[1] = f2b(v0.y); t8[2] = f2b(v0.z); t8[3] = f2b(v0.w);
      t8[4] = f2b(v1.x); t8[5] = f2b(v1.y); t8[6] = f2b(v1.z); t8[7] = f2b(v1.w);
      whh_f[nt][kt] = t8;
    }
#pragma unroll
    for (int kt = 0; kt < 2; kt++) {
      const float4* src = (const float4*)(Wih + G * 64 + kt * 32 + quad * 8);
      float4 v0 = src[0], v1 = src[1];
      ushort8v t8;
      t8[0] = f2b(v0.x); t8[1] = f2b(v0.y); t8[2] = f2b(v0.z); t8[3] = f2b(v0.w);
      t8[4] = f2b(v1.x); t8[5] = f2b(v1.y); t8[6] = f2b(v1.z); t8[7] = f2b(v1.w);
      wih_f[nt][kt] = t8;
    }
  }
  {
    int gg = tid >> 7, cj = tid & 127;          // 512 threads cover [4][128]
    int grow = gg * 256 + p * 128 + cj;
    bias_s[gg][cj] = bih[grow] + bhh[grow];
  }

  const int eb = tid >> 5;    // batch 0..15
  const int ec32 = tid & 31;  // col-within-128 low 5 bits
  float c_reg[4] = {0.f, 0.f, 0.f, 0.f};

  for (int t = 0; t < 128; t++) {
    const int pos = d ? (127 - t) : t;

    // ---- issue x(pos) load (completion hidden under the poll) ----
    const int xf = ec32 * 2;
    float2 xv = *(const float2*)(x + (eb * 128 + pos) * 64 + xf);

    if (t > 0) {
      // ---- poll other WG's 4KB half-slab: 1 coalesced dwordx2/thread ----
      const u32* hw = hbuf + (t * 2 + d) * 2048 + eb * 128 + op * 64 + ec32 * 2;
      uint2v a;
      for (;;) {
        asm volatile(
            "global_load_dwordx2 %0, %1, off sc1\n\t"
            "s_waitcnt vmcnt(0)"
            : "=v"(a) : "v"(hw) : "memory");
        if ((a.x != POISON) & (a.y != POISON)) break;
      }
      // words (op*64 + 2*ec32, +1) -> cols op*128 + 4*ec32 .. +3
      *(u32*)&h_s[eb][op * 128 + ec32 * 4 + 0] = a.x;
      *(u32*)&h_s[eb][op * 128 + ec32 * 4 + 2] = a.y;
    }
    // stage x(pos) -> bf16 LDS
    x_s[eb][xf + 0] = f2b(xv.x);
    x_s[eb][xf + 1] = f2b(xv.y);
    __syncthreads();   // h_s (own-half epilogue writes + polled other half)
                       // and x_s visible to all waves

    // ---- MFMA: 4 n-tiles, A shared per K-frag ----
    f32x4 acc[4];
#pragma unroll
    for (int nt = 0; nt < 4; nt++) acc[nt] = (f32x4){0.f, 0.f, 0.f, 0.f};
#pragma unroll
    for (int kt = 0; kt < 2; kt++) {
      ushort8v av = *(const ushort8v*)&x_s[col16][kt * 32 + quad * 8];
#pragma unroll
      for (int nt = 0; nt < 4; nt++)
        acc[nt] = mfma16(av, wih_f[nt][kt], acc[nt]);
    }
    if (t > 0) {
#pragma unroll
      for (int kt = 0; kt < 8; kt++) {
        ushort8v av = *(const ushort8v*)&h_s[col16][kt * 32 + quad * 8];
#pragma unroll
        for (int nt = 0; nt < 4; nt++)
          acc[nt] = mfma16(av, whh_f[nt][kt], acc[nt]);
      }
    }
#pragma unroll
    for (int nt = 0; nt < 4; nt++)
#pragma unroll
      for (int reg = 0; reg < 4; reg++)
        z_s[g][quad * 4 + reg][s * 64 + nt * 16 + col16] = acc[nt][reg];
    __syncthreads();

    // ---- gate math: 4 cols per thread (cols j*32+ec32), torch i,f,g,o ----
    u32 words[4];
#pragma unroll
    for (int j = 0; j < 4; j++) {
      const int cj = j * 32 + ec32;
      float zi = z_s[0][eb][cj] + bias_s[0][cj];
      float zf = z_s[1][eb][cj] + bias_s[1][cj];
      float zg = z_s[2][eb][cj] + bias_s[2][cj];
      float zo = z_s[3][eb][cj] + bias_s[3][cj];
      float si = sigm(zi), sf = sigm(zf), so = sigm(zo);
      float tg = tanh_f(zg);
      c_reg[j] = sf * c_reg[j] + si * tg;
      float hv = so * tanh_f(c_reg[j]);
      u32 my = (u32)f2b(hv);
      // own-half h for next step's MFMA (local LDS, no fabric RT)
      h_s[eb][p * 128 + cj] = (u16)my;
      u32 hi = ((u32)__shfl_down((int)my, 1)) & 0xFFFFu;  // partner col cj+1
      words[j] = my | (hi << 16);
    }

    if ((ec32 & 1) == 0) {
      // publish FIRST (critical path), then tb
      if (t < 127) {
        const int slab = ((t + 1) * 2 + d) * 2048;
#pragma unroll
        for (int j = 0; j < 4; j++) {
          const int cj = j * 32 + ec32;
          u32* dst = hbuf + slab + eb * 128 + p * 64 + (cj >> 1);
          __hip_atomic_store(dst, words[j], __ATOMIC_RELAXED,
                             __HIP_MEMORY_SCOPE_AGENT);
        }
      }
#pragma unroll
      for (int j = 0; j < 4; j++) {
        const int cj = j * 32 + ec32;
        *(u32*)&tb[(eb * 128 + pos) * 512 + d * 256 + p * 128 + cj] = words[j];
      }
    }
    // no extra barrier: next-iter h_s/x_s writes are ordered by the top
    // barrier; this iter's z_s reads precede it in program order.
  }
}

// ---------------------------------------------------------------------------
// Kernel 2: QKV projection.  out = t @ W^T + bias, M=2048 N=512 K=512.
// grid = (32 Mtiles, 8 Ntiles, 3 which). Q,K,V stored bf16.
// ---------------------------------------------------------------------------
__global__ __launch_bounds__(256) void qkv_kernel(
    const u16* __restrict__ tb,
    const float* __restrict__ Wq, const float* __restrict__ bq,
    const float* __restrict__ Wk, const float* __restrict__ bk,
    const float* __restrict__ Wv, const float* __restrict__ bv,
    u16* __restrict__ Qb, u16* __restrict__ Kb, u16* __restrict__ Vb)
{
  const int tid = threadIdx.x;
  const int bxm = blockIdx.x, byn = blockIdx.y, bz = blockIdx.z;
  const float* W = (bz == 0) ? Wq : ((bz == 1) ? Wk : Wv);
  const float* bias = (bz == 0) ? bq : ((bz == 1) ? bk : bv);
  u16* outp = (bz == 0) ? Qb : ((bz == 1) ? Kb : Vb);

  __shared__ u16 a_s[64][40];
  __shared__ u16 b_s[64][40];
  const int w = tid >> 6, ln = tid & 63, col16 = ln & 15, quad = ln >> 4;

  f32x4 acc[4];
#pragma unroll
  for (int n = 0; n < 4; n++) acc[n] = (f32x4){0.f, 0.f, 0.f, 0.f};

  for (int kt = 0; kt < 16; kt++) {
    int r = tid >> 2, seg = tid & 3;
    *(ushort8v*)&a_s[r][seg * 8] =
        *(const ushort8v*)(tb + (bxm * 64 + r) * 512 + kt * 32 + seg * 8);
    const float4* wsrc = (const float4*)(W + (byn * 64 + r) * 512 + kt * 32 + seg * 8);
    float4 w0 = wsrc[0], w1 = wsrc[1];
    b_s[r][seg * 8 + 0] = f2b(w0.x);
    b_s[r][seg * 8 + 1] = f2b(w0.y);
    b_s[r][seg * 8 + 2] = f2b(w0.z);
    b_s[r][seg * 8 + 3] = f2b(w0.w);
    b_s[r][seg * 8 + 4] = f2b(w1.x);
    b_s[r][seg * 8 + 5] = f2b(w1.y);
    b_s[r][seg * 8 + 6] = f2b(w1.z);
    b_s[r][seg * 8 + 7] = f2b(w1.w);
    __syncthreads();
    ushort8v av = *(const ushort8v*)&a_s[w * 16 + col16][quad * 8];
#pragma unroll
    for (int n = 0; n < 4; n++) {
      ushort8v bvv = *(const ushort8v*)&b_s[n * 16 + col16][quad * 8];
      acc[n] = mfma16(av, bvv, acc[n]);
    }
    __syncthreads();
  }
#pragma unroll
  for (int n = 0; n < 4; n++) {
    float bs = bias[byn * 64 + n * 16 + col16];
#pragma unroll
    for (int reg = 0; reg < 4; reg++) {
      int row = bxm * 64 + w * 16 + quad * 4 + reg;
      outp[row * 512 + byn * 64 + n * 16 + col16] = f2b(acc[n][reg] + bs);
    }
  }
}

// ---------------------------------------------------------------------------
// Kernel 3: scores + softmax -> attn (d_out, f32). grid = (16 b, 4 h, 2 qhalf).
// Epilogue: per-row inv staged in LDS, cooperative coalesced float4 stores.
// ---------------------------------------------------------------------------
__global__ __launch_bounds__(256) void attn_kernel(
    const u16* __restrict__ Qb, const u16* __restrict__ Kb,
    float* __restrict__ attn_out)
{
  const int b = blockIdx.x, h = blockIdx.y, half = blockIdx.z;
  const int tid = threadIdx.x;
  __shared__ __align__(16) char smem[52224];
  __shared__ float inv_s[64];
  u16 (*q_s)[136] = (u16(*)[136])smem;
  u16 (*k_s)[136] = (u16(*)[136])(smem + 17408);
  float (*sc)[132] = (float(*)[132])smem;  // reused after MFMA

  const int w = tid >> 6, ln = tid & 63, col16 = ln & 15, quad = ln >> 4;
  {
    int r = tid >> 2, seg = tid & 3;
    const u16* src = Qb + (b * 128 + half * 64 + r) * 512 + h * 128 + seg * 32;
#pragma unroll
    for (int i = 0; i < 4; i++)
      *(ushort8v*)&q_s[r][seg * 32 + i * 8] = *(const ushort8v*)(src + i * 8);
    int r2 = tid >> 1, sg = tid & 1;
    const u16* src2 = Kb + (b * 128 + r2) * 512 + h * 128 + sg * 64;
#pragma unroll
    for (int i = 0; i < 8; i++)
      *(ushort8v*)&k_s[r2][sg * 64 + i * 8] = *(const ushort8v*)(src2 + i * 8);
  }
  __syncthreads();

  f32x4 acc[8];
#pragma unroll
  for (int n = 0; n < 8; n++) acc[n] = (f32x4){0.f, 0.f, 0.f, 0.f};
#pragma unroll
  for (int kd = 0; kd < 4; kd++) {
    ushort8v av = *(const ushort8v*)&q_s[w * 16 + col16][kd * 32 + quad * 8];
#pragma unroll
    for (int n = 0; n < 8; n++) {
      ushort8v bvv = *(const ushort8v*)&k_s[n * 16 + col16][kd * 32 + quad * 8];
      acc[n] = mfma16(av, bvv, acc[n]);
    }
  }
  __syncthreads();  // done with q_s/k_s before overwriting with sc
  const float scale = 0.08838834764831845f;  // 1/sqrt(128)
#pragma unroll
  for (int n = 0; n < 8; n++)
#pragma unroll
    for (int reg = 0; reg < 4; reg++)
      sc[w * 16 + quad * 4 + reg][n * 16 + col16] = acc[n][reg] * scale;
  __syncthreads();

  const int row = tid >> 2, p = tid & 3;
  float m = -1e30f;
  for (int c0 = 0; c0 < 32; c0++) m = fmaxf(m, sc[row][p * 32 + c0]);
  m = fmaxf(m, __shfl_xor(m, 1));
  m = fmaxf(m, __shfl_xor(m, 2));
  float s = 0.f;
  for (int c0 = 0; c0 < 32; c0++) {
    float e = __expf(sc[row][p * 32 + c0] - m);
    sc[row][p * 32 + c0] = e;
    s += e;
  }
  s += __shfl_xor(s, 1);
  s += __shfl_xor(s, 2);
  if (p == 0) inv_s[row] = 1.f / s;
  __syncthreads();

  // cooperative coalesced store: 64 rows x 128 f32
  float* obase = attn_out + (size_t)((b * 4 + h) * 128 + half * 64) * 128;
#pragma unroll
  for (int it = 0; it < 8; it++) {
    int idx = tid + it * 256;     // 0..2047
    int r = idx >> 5;             // row 0..63
    int c4 = idx & 31;            // float4 index 0..31
    float4 ev = *(float4*)&sc[r][c4 * 4];
    float iv = inv_s[r];
    float4 ov = {ev.x * iv, ev.y * iv, ev.z * iv, ev.w * iv};
    *(float4*)&obase[r * 128 + c4 * 4] = ov;
  }
}

// ---------------------------------------------------------------------------
// Kernel 4 (merged aolast+fuse): ao (q=127 only), last = ao@Wo^T+bo,
// collapsed GAT (2 dense layers), fusion Linear + LayerNorm + ReLU.
// grid = 16 (batch), 256 threads.
// ---------------------------------------------------------------------------
__global__ __launch_bounds__(256) void tail_kernel(
    const float* __restrict__ attn, const u16* __restrict__ Vb,
    const float* __restrict__ Wo, const float* __restrict__ bo,
    const float* __restrict__ W1, const float* __restrict__ b1,
    const float* __restrict__ g1, const float* __restrict__ be1,
    const float* __restrict__ W2, const float* __restrict__ pb2,
    const float* __restrict__ g2, const float* __restrict__ be2,
    const float* __restrict__ Wf, const float* __restrict__ bfv,
    const float* __restrict__ ln_g, const float* __restrict__ ln_b,
    float* __restrict__ dout)
{
  const int b = blockIdx.x, tid = threadIdx.x;
  __shared__ float arow[4][128];
  __shared__ float ao_s[512];
  __shared__ float last_s[512];
  __shared__ float h_s2[256];
  __shared__ float red_s[4];

  // ---- ao row (q=127) ----
#pragma unroll
  for (int e = 0; e < 2; e++) {
    int idx = tid + e * 256;
    int h = idx >> 7, k = idx & 127;
    arow[h][k] = attn[((b * 4 + h) * 128 + 127) * 128 + k];
  }
  __syncthreads();
#pragma unroll
  for (int pass = 0; pass < 2; pass++) {
    int d2 = tid + pass * 256;
    int hh = d2 >> 7;
    float acc = 0.f;
    for (int k = 0; k < 128; k++)
      acc += arow[hh][k] * b2f(Vb[(b * 128 + k) * 512 + d2]);
    ao_s[d2] = acc;
  }
  __syncthreads();
  // ---- last = ao @ Wo^T + bo ----
#pragma unroll
  for (int pass = 0; pass < 2; pass++) {
    int j = tid + pass * 256;
    float acc = bo[j];
    const float4* Wo4 = (const float4*)(Wo + j * 512);
    for (int k4 = 0; k4 < 128; k4++) {
      float4 wv = Wo4[k4];
      acc += ao_s[k4 * 4 + 0] * wv.x + ao_s[k4 * 4 + 1] * wv.y +
             ao_s[k4 * 4 + 2] * wv.z + ao_s[k4 * 4 + 3] * wv.w;
    }
    last_s[j] = acc;
  }
  __syncthreads();

  // ---- collapsed GAT layer 1 ----
  const int j = tid;
  float acc = 0.f;
  for (int k = 0; k < 512; k++) acc += last_s[k] * W1[k * 256 + j];
  float u = (acc + b1[j]) * BN_INV_F * g1[j] + be1[j];
  float h1 = u > 0.f ? u : expm1f(u);
  h_s2[j] = h1;
  __syncthreads();

  // ---- collapsed GAT layer 2 ----
  float acc2 = 0.f;
  for (int k = 0; k < 256; k++) acc2 += h_s2[k] * W2[k * 256 + j];
  float u2 = (acc2 + pb2[j]) * BN_INV_F * g2[j] + be2[j];
  float sp = u2 > 0.f ? u2 : expm1f(u2);
  __syncthreads();
  h_s2[j] = sp;
  __syncthreads();

  // ---- fusion Linear ----
  float f = bfv[j];
  const float4* Wf4 = (const float4*)(Wf + j * 768);
  for (int k4 = 0; k4 < 128; k4++) {
    float4 wv = Wf4[k4];
    f += last_s[k4 * 4 + 0] * wv.x + last_s[k4 * 4 + 1] * wv.y +
         last_s[k4 * 4 + 2] * wv.z + last_s[k4 * 4 + 3] * wv.w;
  }
  for (int k4 = 0; k4 < 64; k4++) {
    float4 wv = Wf4[128 + k4];
    f += h_s2[k4 * 4 + 0] * wv.x + h_s2[k4 * 4 + 1] * wv.y +
         h_s2[k4 * 4 + 2] * wv.z + h_s2[k4 * 4 + 3] * wv.w;
  }

  // ---- LayerNorm + ReLU ----
  float v = f;
#pragma unroll
  for (int o = 32; o > 0; o >>= 1) v += __shfl_xor(v, o);
  if ((tid & 63) == 0) red_s[tid >> 6] = v;
  __syncthreads();
  float mu = (red_s[0] + red_s[1] + red_s[2] + red_s[3]) * (1.f / 256.f);
  float dv = f - mu;
  float vv = dv * dv;
#pragma unroll
  for (int o = 32; o > 0; o >>= 1) vv += __shfl_xor(vv, o);
  __syncthreads();
  if ((tid & 63) == 0) red_s[tid >> 6] = vv;
  __syncthreads();
  float var = (red_s[0] + red_s[1] + red_s[2] + red_s[3]) * (1.f / 256.f);
  float y = dv * rsqrtf(var + 1e-5f) * ln_g[j] + ln_b[j];
  dout[b * 256 + j] = fmaxf(y, 0.f);
}

// ---------------------------------------------------------------------------
// ws layout (bytes):
//   0         hbuf  [128][2][16][128] u32   2097152  (memset 0xFF each call)
//   2129920   tb    [16][128][512] bf16     2097152
//   4227072   Q     [2048][512] bf16        2097152
//   6324224   K     [2048][512] bf16        2097152
//   8421376   V     [2048][512] bf16        2097152  -> total 10518528 bytes
// ---------------------------------------------------------------------------
extern "C" void kernel_launch(void* const* d_in, const int* in_sizes, int n_in,
                              void* d_out, int out_size, void* d_ws, size_t ws_size,
                              hipStream_t stream) {
  (void)in_sizes; (void)n_in; (void)out_size; (void)ws_size;
  const float* x     = (const float*)d_in[0];
  const float* Wih_f = (const float*)d_in[2];
  const float* Whh_f = (const float*)d_in[3];
  const float* bih_f = (const float*)d_in[4];
  const float* bhh_f = (const float*)d_in[5];
  const float* Wih_b = (const float*)d_in[6];
  const float* Whh_b = (const float*)d_in[7];
  const float* bih_b = (const float*)d_in[8];
  const float* bhh_b = (const float*)d_in[9];
  const float* Wq = (const float*)d_in[10]; const float* bq = (const float*)d_in[11];
  const float* Wk = (const float*)d_in[12]; const float* bk = (const float*)d_in[13];
  const float* Wv = (const float*)d_in[14]; const float* bv = (const float*)d_in[15];
  const float* Wo = (const float*)d_in[16]; const float* bo = (const float*)d_in[17];
  const float* W1 = (const float*)d_in[18];
  const float* b1 = (const float*)d_in[21];
  const float* g1 = (const float*)d_in[22]; const float* be1 = (const float*)d_in[23];
  const float* W2 = (const float*)d_in[24];
  const float* pb2 = (const float*)d_in[27];
  const float* g2 = (const float*)d_in[28]; const float* be2 = (const float*)d_in[29];
  const float* Wf = (const float*)d_in[30]; const float* bfv = (const float*)d_in[31];
  const float* ln_g = (const float*)d_in[32]; const float* ln_b = (const float*)d_in[33];

  float* dout = (float*)d_out;
  char* ws = (char*)d_ws;
  u32* hbuf = (u32*)(ws + 0);
  u16* tb   = (u16*)(ws + 2129920);
  u16* Qb   = (u16*)(ws + 4227072);
  u16* Kb   = (u16*)(ws + 6324224);
  u16* Vb   = (u16*)(ws + 8421376);

  (void)hipMemsetAsync(ws, 0xFF, 2097152, stream);  // poison hbuf ring
  lstm_kernel<<<4, 512, 0, stream>>>(x, Wih_f, Whh_f, bih_f, bhh_f,
                                     Wih_b, Whh_b, bih_b, bhh_b,
                                     hbuf, tb);
  qkv_kernel<<<dim3(32, 8, 3), 256, 0, stream>>>(tb, Wq, bq, Wk, bk, Wv, bv,
                                                 Qb, Kb, Vb);
  attn_kernel<<<dim3(16, 4, 2), 256, 0, stream>>>(Qb, Kb, dout + 4096);
  tail_kernel<<<16, 256, 0, stream>>>(dout + 4096, Vb, Wo, bo,
                                      W1, b1, g1, be1, W2, pb2, g2, be2,
                                      Wf, bfv, ln_g, ln_b, dout);
}

// Round 9
// 504.562 us; speedup vs baseline: 1.3226x; 1.2522x over previous
//
#include <hip/hip_runtime.h>

// ---------------------------------------------------------------------------
// SpatioTemporalBlock: biLSTM -> temporal MHA -> (collapsed) GAT -> fusion
// B=16 S=128 F=64 H=256 HEADS=4 DH=64 AH=128 D2=512
// FP32 inputs/outputs; MFMA operands converted f32->bf16 at staging.
// GAT collapses: broadcast node features => uniform alpha => dense layers.
//
// v9 = v5 lstm/attn (verified 212us lstm, 433us total) + tail/qkv rework:
//   - lstm: byte-identical to v5 (register-resident Whh/Wih B-frags, x load
//     issued before the coalesced sc1 poison poll, v1 publish geometry).
//     Fabric floor ~212us (127 sequential MALL RTs); all 6 variants lost.
//   - qkv: double-buffered LDS ping-pong -> 1 barrier per K-tile (was 2),
//     staging overlapped with MFMA.
//   - tail: 512 threads (2 waves/SIMD latency hiding, was 1). ao/last are
//     single-pass; GAT1/GAT2/fusion GEMVs use 2-way k-split + LDS combine;
//     LayerNorm reduce widened to 8 waves (upper half zero-padded).
// hbuf ring [128 steps][2 dir][16 b][256 c] bf16, memset 0xFF per launch;
// h never hits the NaN bit pattern (bounded by sigmoid*tanh).
// ---------------------------------------------------------------------------

typedef unsigned short u16;
typedef unsigned int u32;
typedef __bf16 bf16x8 __attribute__((ext_vector_type(8)));
typedef float f32x4 __attribute__((ext_vector_type(4)));
typedef unsigned short ushort8v __attribute__((ext_vector_type(8)));
typedef unsigned int uint4v __attribute__((ext_vector_type(4)));

#define BN_INV_F 0.9999950000374997f
#define POISON 0xFFFFFFFFu

__device__ __forceinline__ float b2f(u16 u) {
  union { float f; unsigned int i; } v;
  v.i = ((unsigned int)u) << 16;
  return v.f;
}
__device__ __forceinline__ u16 f2b(float f) {
  union { float f; unsigned int i; } v;
  v.f = f;
  unsigned int x = v.i;
  unsigned int r = (x + 0x7FFFu + ((x >> 16) & 1u)) >> 16;
  return (u16)r;
}
__device__ __forceinline__ f32x4 mfma16(ushort8v a, ushort8v b, f32x4 c) {
  return __builtin_amdgcn_mfma_f32_16x16x32_bf16(
      __builtin_bit_cast(bf16x8, a), __builtin_bit_cast(bf16x8, b), c, 0, 0, 0);
}
__device__ __forceinline__ float sigm(float x) { return 1.f / (1.f + __expf(-x)); }
__device__ __forceinline__ float tanh_f(float x) {
  float e = __expf(2.f * x);
  return 1.f - 2.f / (e + 1.f);
}

// ---------------------------------------------------------------------------
// Kernel 1: bidirectional LSTM (v5 verbatim). grid = 32: dir=bx>>4, q=bx&15.
// ---------------------------------------------------------------------------
__global__ __launch_bounds__(256) void lstm_kernel(
    const float* __restrict__ x,
    const float* __restrict__ Wih0, const float* __restrict__ Whh0,
    const float* __restrict__ bih0, const float* __restrict__ bhh0,
    const float* __restrict__ Wih1, const float* __restrict__ Whh1,
    const float* __restrict__ bih1, const float* __restrict__ bhh1,
    u32* __restrict__ hbuf,   // [128][2][16][128] u32 view (poisoned 0xFF)
    u16* __restrict__ tb)     // [16][128][512] bf16
{
  const int tid = threadIdx.x;
  const int bx = blockIdx.x;
  const int d = bx >> 4;
  const int q = bx & 15;
  const float* Wih = d ? Wih1 : Wih0;
  const float* Whh = d ? Whh1 : Whh0;
  const float* bih = d ? bih1 : bih0;
  const float* bhh = d ? bhh1 : bhh0;

  const int w = tid >> 6;
  const int ln = tid & 63;
  const int col16 = ln & 15;
  const int quad = ln >> 4;

  __shared__ u16 h_s[16][264];
  __shared__ u16 x_s[16][72];
  __shared__ float z_s[4][16][17];
  __shared__ float bias_s[64];

  // ---- stage weights into registers (bf16 fragments), v1 row mapping ----
  const int G = w * 256 + q * 16 + col16;   // row w*16+col16 of this chunk
  ushort8v whh_f[8];
#pragma unroll
  for (int kt = 0; kt < 8; kt++) {
    const float4* src = (const float4*)(Whh + G * 256 + kt * 32 + quad * 8);
    float4 v0 = src[0], v1 = src[1];
    ushort8v t8;
    t8[0] = f2b(v0.x); t8[1] = f2b(v0.y); t8[2] = f2b(v0.z); t8[3] = f2b(v0.w);
    t8[4] = f2b(v1.x); t8[5] = f2b(v1.y); t8[6] = f2b(v1.z); t8[7] = f2b(v1.w);
    whh_f[kt] = t8;
  }
  ushort8v wih_f[2];
#pragma unroll
  for (int kt = 0; kt < 2; kt++) {
    const float4* src = (const float4*)(Wih + G * 64 + kt * 32 + quad * 8);
    float4 v0 = src[0], v1 = src[1];
    ushort8v t8;
    t8[0] = f2b(v0.x); t8[1] = f2b(v0.y); t8[2] = f2b(v0.z); t8[3] = f2b(v0.w);
    t8[4] = f2b(v1.x); t8[5] = f2b(v1.y); t8[6] = f2b(v1.z); t8[7] = f2b(v1.w);
    wih_f[kt] = t8;
  }
  if (tid < 64) {
    int grow = ((tid >> 4) << 8) + q * 16 + (tid & 15);
    bias_s[tid] = bih[grow] + bhh[grow];
  }

  const int eb = tid >> 4;  // elementwise: batch
  const int ec = tid & 15;  // elementwise: h-col within chunk
  float c_reg = 0.f;

  for (int t = 0; t < 128; t++) {
    const int pos = d ? (127 - t) : t;

    // ---- issue x(pos) load (completion hidden under the poll) ----
    float4 xv = *(const float4*)(x + (eb * 128 + pos) * 64 + ec * 4);

    if (t > 0) {
      // poll full h(t): 8 u32 words per thread via 2 coalesced sc1 x4 loads
      const u32* hw = hbuf + (t * 2 + d) * 2048 + tid * 8;
      uint4v a, b;
      for (;;) {
        asm volatile(
            "global_load_dwordx4 %0, %2, off sc1\n\t"
            "global_load_dwordx4 %1, %3, off sc1\n\t"
            "s_waitcnt vmcnt(0)"
            : "=v"(a), "=v"(b)
            : "v"(hw), "v"(hw + 4)
            : "memory");
        bool ok = (a.x != POISON) & (a.y != POISON) & (a.z != POISON) &
                  (a.w != POISON) & (b.x != POISON) & (b.y != POISON) &
                  (b.z != POISON) & (b.w != POISON);
        if (ok) break;
      }
      int b_ = tid >> 4, c0 = (tid & 15) * 16;
      *(u32*)&h_s[b_][c0 + 0] = a.x;
      *(u32*)&h_s[b_][c0 + 2] = a.y;
      *(u32*)&h_s[b_][c0 + 4] = a.z;
      *(u32*)&h_s[b_][c0 + 6] = a.w;
      *(u32*)&h_s[b_][c0 + 8] = b.x;
      *(u32*)&h_s[b_][c0 + 10] = b.y;
      *(u32*)&h_s[b_][c0 + 12] = b.z;
      *(u32*)&h_s[b_][c0 + 14] = b.w;
    }
    // stage x(pos) -> bf16 LDS (data already in flight / arrived)
    {
      int f0 = ec * 4;
      x_s[eb][f0 + 0] = f2b(xv.x);
      x_s[eb][f0 + 1] = f2b(xv.y);
      x_s[eb][f0 + 2] = f2b(xv.z);
      x_s[eb][f0 + 3] = f2b(xv.w);
    }
    __syncthreads();

    f32x4 acc = {0.f, 0.f, 0.f, 0.f};
#pragma unroll
    for (int kt = 0; kt < 2; kt++) {
      ushort8v av = *(const ushort8v*)&x_s[col16][kt * 32 + quad * 8];
      acc = mfma16(av, wih_f[kt], acc);
    }
    if (t > 0) {
#pragma unroll
      for (int kt = 0; kt < 8; kt++) {
        ushort8v av = *(const ushort8v*)&h_s[col16][kt * 32 + quad * 8];
        acc = mfma16(av, whh_f[kt], acc);
      }
    }
#pragma unroll
    for (int reg = 0; reg < 4; reg++)
      z_s[w][quad * 4 + reg][col16] = acc[reg];
    __syncthreads();

    // gates: torch order i, f, g, o (f32) — one element per thread
    float zi = z_s[0][eb][ec] + bias_s[ec];
    float zf = z_s[1][eb][ec] + bias_s[16 + ec];
    float zg = z_s[2][eb][ec] + bias_s[32 + ec];
    float zo = z_s[3][eb][ec] + bias_s[48 + ec];
    float si = sigm(zi), sf = sigm(zf), so = sigm(zo);
    float tg = tanh_f(zg);
    c_reg = sf * c_reg + si * tg;
    float hv = so * tanh_f(c_reg);
    u32 my = (u32)f2b(hv);
    u32 hi = __shfl_down((int)my, 1);  // partner col (ec+1), same wave
    if ((ec & 1) == 0) {
      u32 word = my | (hi << 16);
      *(u32*)&tb[(eb * 128 + pos) * 512 + d * 256 + q * 16 + ec] = word;
      if (t < 127) {
        u32* dst = hbuf + ((t + 1) * 2 + d) * 2048 + eb * 128 + (q * 16 + ec) / 2;
        __hip_atomic_store(dst, word, __ATOMIC_RELAXED,
                           __HIP_MEMORY_SCOPE_AGENT);
      }
    }
    // no extra barrier: next-iter writes touch x_s/h_s only, whose reads all
    // completed before the z_s barrier above.
  }
}

// ---------------------------------------------------------------------------
// Kernel 2: QKV projection.  out = t @ W^T + bias, M=2048 N=512 K=512.
// grid = (32 Mtiles, 8 Ntiles, 3 which). Double-buffered LDS: 1 barrier/kt.
// ---------------------------------------------------------------------------
__global__ __launch_bounds__(256) void qkv_kernel(
    const u16* __restrict__ tb,
    const float* __restrict__ Wq, const float* __restrict__ bq,
    const float* __restrict__ Wk, const float* __restrict__ bk,
    const float* __restrict__ Wv, const float* __restrict__ bv,
    u16* __restrict__ Qb, u16* __restrict__ Kb, u16* __restrict__ Vb)
{
  const int tid = threadIdx.x;
  const int bxm = blockIdx.x, byn = blockIdx.y, bz = blockIdx.z;
  const float* W = (bz == 0) ? Wq : ((bz == 1) ? Wk : Wv);
  const float* bias = (bz == 0) ? bq : ((bz == 1) ? bk : bv);
  u16* outp = (bz == 0) ? Qb : ((bz == 1) ? Kb : Vb);

  __shared__ u16 a_s[2][64][40];
  __shared__ u16 b_s[2][64][40];
  const int w = tid >> 6, ln = tid & 63, col16 = ln & 15, quad = ln >> 4;
  const int r = tid >> 2, seg = tid & 3;

#define QKV_STAGE(buf, kt)                                                    \
  do {                                                                        \
    *(ushort8v*)&a_s[buf][r][seg * 8] =                                       \
        *(const ushort8v*)(tb + (bxm * 64 + r) * 512 + (kt) * 32 + seg * 8);  \
    const float4* wsrc =                                                      \
        (const float4*)(W + (byn * 64 + r) * 512 + (kt) * 32 + seg * 8);      \
    float4 w0 = wsrc[0], w1 = wsrc[1];                                        \
    b_s[buf][r][seg * 8 + 0] = f2b(w0.x);                                     \
    b_s[buf][r][seg * 8 + 1] = f2b(w0.y);                                     \
    b_s[buf][r][seg * 8 + 2] = f2b(w0.z);                                     \
    b_s[buf][r][seg * 8 + 3] = f2b(w0.w);                                     \
    b_s[buf][r][seg * 8 + 4] = f2b(w1.x);                                     \
    b_s[buf][r][seg * 8 + 5] = f2b(w1.y);                                     \
    b_s[buf][r][seg * 8 + 6] = f2b(w1.z);                                     \
    b_s[buf][r][seg * 8 + 7] = f2b(w1.w);                                     \
  } while (0)

  f32x4 acc[4];
#pragma unroll
  for (int n = 0; n < 4; n++) acc[n] = (f32x4){0.f, 0.f, 0.f, 0.f};

  QKV_STAGE(0, 0);
  __syncthreads();
  for (int kt = 0; kt < 16; kt++) {
    const int cur = kt & 1;
    if (kt < 15) QKV_STAGE(cur ^ 1, kt + 1);  // overlap next-tile staging
    ushort8v av = *(const ushort8v*)&a_s[cur][w * 16 + col16][quad * 8];
#pragma unroll
    for (int n = 0; n < 4; n++) {
      ushort8v bvv = *(const ushort8v*)&b_s[cur][n * 16 + col16][quad * 8];
      acc[n] = mfma16(av, bvv, acc[n]);
    }
    __syncthreads();  // staged (kt+1) visible; cur reads done before re-stage
  }
#undef QKV_STAGE
#pragma unroll
  for (int n = 0; n < 4; n++) {
    float bs = bias[byn * 64 + n * 16 + col16];
#pragma unroll
    for (int reg = 0; reg < 4; reg++) {
      int row = bxm * 64 + w * 16 + quad * 4 + reg;
      outp[row * 512 + byn * 64 + n * 16 + col16] = f2b(acc[n][reg] + bs);
    }
  }
}

// ---------------------------------------------------------------------------
// Kernel 3: scores + softmax -> attn (d_out, f32). grid = (16 b, 4 h, 2 qhalf).
// (v5 verbatim; coalesced epilogue)
// ---------------------------------------------------------------------------
__global__ __launch_bounds__(256) void attn_kernel(
    const u16* __restrict__ Qb, const u16* __restrict__ Kb,
    float* __restrict__ attn_out)
{
  const int b = blockIdx.x, h = blockIdx.y, half = blockIdx.z;
  const int tid = threadIdx.x;
  __shared__ __align__(16) char smem[52224];
  __shared__ float inv_s[64];
  u16 (*q_s)[136] = (u16(*)[136])smem;
  u16 (*k_s)[136] = (u16(*)[136])(smem + 17408);
  float (*sc)[132] = (float(*)[132])smem;  // reused after MFMA

  const int w = tid >> 6, ln = tid & 63, col16 = ln & 15, quad = ln >> 4;
  {
    int r = tid >> 2, seg = tid & 3;
    const u16* src = Qb + (b * 128 + half * 64 + r) * 512 + h * 128 + seg * 32;
#pragma unroll
    for (int i = 0; i < 4; i++)
      *(ushort8v*)&q_s[r][seg * 32 + i * 8] = *(const ushort8v*)(src + i * 8);
    int r2 = tid >> 1, sg = tid & 1;
    const u16* src2 = Kb + (b * 128 + r2) * 512 + h * 128 + sg * 64;
#pragma unroll
    for (int i = 0; i < 8; i++)
      *(ushort8v*)&k_s[r2][sg * 64 + i * 8] = *(const ushort8v*)(src2 + i * 8);
  }
  __syncthreads();

  f32x4 acc[8];
#pragma unroll
  for (int n = 0; n < 8; n++) acc[n] = (f32x4){0.f, 0.f, 0.f, 0.f};
#pragma unroll
  for (int kd = 0; kd < 4; kd++) {
    ushort8v av = *(const ushort8v*)&q_s[w * 16 + col16][kd * 32 + quad * 8];
#pragma unroll
    for (int n = 0; n < 8; n++) {
      ushort8v bvv = *(const ushort8v*)&k_s[n * 16 + col16][kd * 32 + quad * 8];
      acc[n] = mfma16(av, bvv, acc[n]);
    }
  }
  __syncthreads();  // done with q_s/k_s before overwriting with sc
  const float scale = 0.08838834764831845f;  // 1/sqrt(128)
#pragma unroll
  for (int n = 0; n < 8; n++)
#pragma unroll
    for (int reg = 0; reg < 4; reg++)
      sc[w * 16 + quad * 4 + reg][n * 16 + col16] = acc[n][reg] * scale;
  __syncthreads();

  const int row = tid >> 2, p = tid & 3;
  float m = -1e30f;
  for (int c0 = 0; c0 < 32; c0++) m = fmaxf(m, sc[row][p * 32 + c0]);
  m = fmaxf(m, __shfl_xor(m, 1));
  m = fmaxf(m, __shfl_xor(m, 2));
  float s = 0.f;
  for (int c0 = 0; c0 < 32; c0++) {
    float e = __expf(sc[row][p * 32 + c0] - m);
    sc[row][p * 32 + c0] = e;
    s += e;
  }
  s += __shfl_xor(s, 1);
  s += __shfl_xor(s, 2);
  if (p == 0) inv_s[row] = 1.f / s;
  __syncthreads();

  // cooperative coalesced store: 64 rows x 128 f32
  float* obase = attn_out + (size_t)((b * 4 + h) * 128 + half * 64) * 128;
#pragma unroll
  for (int it = 0; it < 8; it++) {
    int idx = tid + it * 256;     // 0..2047
    int r = idx >> 5;             // row 0..63
    int c4 = idx & 31;            // float4 index 0..31
    float4 ev = *(float4*)&sc[r][c4 * 4];
    float iv = inv_s[r];
    float4 ov = {ev.x * iv, ev.y * iv, ev.z * iv, ev.w * iv};
    *(float4*)&obase[r * 128 + c4 * 4] = ov;
  }
}

// ---------------------------------------------------------------------------
// Kernel 4: ao (q=127 only), last = ao@Wo^T+bo, collapsed GAT, fusion.
// grid = 16 (batch), 512 threads (2 waves/SIMD latency hiding).
// GEMV loops 2-way k-split: half = tid>>8, j = tid&255, combine via part[].
// ---------------------------------------------------------------------------
__global__ __launch_bounds__(512) void tail_kernel(
    const float* __restrict__ attn, const u16* __restrict__ Vb,
    const float* __restrict__ Wo, const float* __restrict__ bo,
    const float* __restrict__ W1, const float* __restrict__ b1,
    const float* __restrict__ g1, const float* __restrict__ be1,
    const float* __restrict__ W2, const float* __restrict__ pb2,
    const float* __restrict__ g2, const float* __restrict__ be2,
    const float* __restrict__ Wf, const float* __restrict__ bfv,
    const float* __restrict__ ln_g, const float* __restrict__ ln_b,
    float* __restrict__ dout)
{
  const int b = blockIdx.x, tid = threadIdx.x;
  const int half = tid >> 8;       // k-split half
  const int j = tid & 255;         // output col for 256-wide stages
  __shared__ float arow[4][128];
  __shared__ float ao_s[512];
  __shared__ float last_s[512];
  __shared__ float h_s2[256];
  __shared__ float part[2][256];
  __shared__ float red_s[8];

  // ---- ao row (q=127): single pass, 512 threads ----
  {
    int hh = tid >> 7, k = tid & 127;
    arow[hh][k] = attn[((b * 4 + hh) * 128 + 127) * 128 + k];
  }
  __syncthreads();
  {
    int d2 = tid;
    int hh = d2 >> 7;
    float acc = 0.f;
    for (int k = 0; k < 128; k++)
      acc += arow[hh][k] * b2f(Vb[(b * 128 + k) * 512 + d2]);
    ao_s[d2] = acc;
  }
  __syncthreads();
  // ---- last = ao @ Wo^T + bo: single pass, 512 outputs ----
  {
    float acc = bo[tid];
    const float4* Wo4 = (const float4*)(Wo + tid * 512);
    for (int k4 = 0; k4 < 128; k4++) {
      float4 wv = Wo4[k4];
      acc += ao_s[k4 * 4 + 0] * wv.x + ao_s[k4 * 4 + 1] * wv.y +
             ao_s[k4 * 4 + 2] * wv.z + ao_s[k4 * 4 + 3] * wv.w;
    }
    last_s[tid] = acc;
  }
  __syncthreads();

  // ---- collapsed GAT layer 1 (k-split 2x256) ----
  {
    float acc = 0.f;
    const int k0 = half * 256;
    for (int k = k0; k < k0 + 256; k++) acc += last_s[k] * W1[k * 256 + j];
    part[half][j] = acc;
  }
  __syncthreads();
  if (tid < 256) {
    float u = (part[0][tid] + part[1][tid] + b1[tid]) * BN_INV_F * g1[tid] + be1[tid];
    h_s2[tid] = u > 0.f ? u : expm1f(u);
  }
  __syncthreads();

  // ---- collapsed GAT layer 2 (k-split 2x128) ----
  {
    float acc2 = 0.f;
    const int k0 = half * 128;
    for (int k = k0; k < k0 + 128; k++) acc2 += h_s2[k] * W2[k * 256 + j];
    part[half][j] = acc2;
  }
  __syncthreads();
  if (tid < 256) {
    float u2 = (part[0][tid] + part[1][tid] + pb2[tid]) * BN_INV_F * g2[tid] + be2[tid];
    float sp = u2 > 0.f ? u2 : expm1f(u2);
    h_s2[tid] = sp;                 // all GAT2 k-reads done at barrier above
  }
  __syncthreads();

  // ---- fusion Linear (k-split: half0 = last_s[0:384), half1 = rest) ----
  {
    float f = 0.f;
    const float4* Wf4 = (const float4*)(Wf + j * 768);
    if (half == 0) {
      for (int k4 = 0; k4 < 96; k4++) {
        float4 wv = Wf4[k4];
        f += last_s[k4 * 4 + 0] * wv.x + last_s[k4 * 4 + 1] * wv.y +
             last_s[k4 * 4 + 2] * wv.z + last_s[k4 * 4 + 3] * wv.w;
      }
    } else {
      for (int k4 = 96; k4 < 128; k4++) {
        float4 wv = Wf4[k4];
        f += last_s[k4 * 4 + 0] * wv.x + last_s[k4 * 4 + 1] * wv.y +
             last_s[k4 * 4 + 2] * wv.z + last_s[k4 * 4 + 3] * wv.w;
      }
      for (int k4 = 128; k4 < 192; k4++) {
        float4 wv = Wf4[k4];
        int m = (k4 - 128) * 4;
        f += h_s2[m + 0] * wv.x + h_s2[m + 1] * wv.y +
             h_s2[m + 2] * wv.z + h_s2[m + 3] * wv.w;
      }
    }
    part[half][j] = f;
  }
  __syncthreads();

  // ---- LayerNorm + ReLU (lower 256 hold values; upper contribute 0) ----
  float fv = 0.f;
  if (tid < 256) fv = part[0][tid] + part[1][tid] + bfv[tid];
  float v = fv;
#pragma unroll
  for (int o = 32; o > 0; o >>= 1) v += __shfl_xor(v, o);
  if ((tid & 63) == 0) red_s[tid >> 6] = v;
  __syncthreads();
  float mu = (red_s[0] + red_s[1] + red_s[2] + red_s[3] +
              red_s[4] + red_s[5] + red_s[6] + red_s[7]) * (1.f / 256.f);
  float dv = fv - mu;
  float vv = (tid < 256) ? dv * dv : 0.f;
#pragma unroll
  for (int o = 32; o > 0; o >>= 1) vv += __shfl_xor(vv, o);
  __syncthreads();
  if ((tid & 63) == 0) red_s[tid >> 6] = vv;
  __syncthreads();
  float var = (red_s[0] + red_s[1] + red_s[2] + red_s[3] +
               red_s[4] + red_s[5] + red_s[6] + red_s[7]) * (1.f / 256.f);
  if (tid < 256) {
    float y = dv * rsqrtf(var + 1e-5f) * ln_g[tid] + ln_b[tid];
    dout[b * 256 + tid] = fmaxf(y, 0.f);
  }
}

// ---------------------------------------------------------------------------
// ws layout (bytes):
//   0         hbuf  [128][2][16][256] bf16  2097152  (memset 0xFF each call)
//   2129920   tb    [16][128][512] bf16     2097152
//   4227072   Q     [2048][512] bf16        2097152
//   6324224   K     [2048][512] bf16        2097152
//   8421376   V     [2048][512] bf16        2097152  -> total 10518528 bytes
// ---------------------------------------------------------------------------
extern "C" void kernel_launch(void* const* d_in, const int* in_sizes, int n_in,
                              void* d_out, int out_size, void* d_ws, size_t ws_size,
                              hipStream_t stream) {
  (void)in_sizes; (void)n_in; (void)out_size; (void)ws_size;
  const float* x     = (const float*)d_in[0];
  const float* Wih_f = (const float*)d_in[2];
  const float* Whh_f = (const float*)d_in[3];
  const float* bih_f = (const float*)d_in[4];
  const float* bhh_f = (const float*)d_in[5];
  const float* Wih_b = (const float*)d_in[6];
  const float* Whh_b = (const float*)d_in[7];
  const float* bih_b = (const float*)d_in[8];
  const float* bhh_b = (const float*)d_in[9];
  const float* Wq = (const float*)d_in[10]; const float* bq = (const float*)d_in[11];
  const float* Wk = (const float*)d_in[12]; const float* bk = (const float*)d_in[13];
  const float* Wv = (const float*)d_in[14]; const float* bv = (const float*)d_in[15];
  const float* Wo = (const float*)d_in[16]; const float* bo = (const float*)d_in[17];
  const float* W1 = (const float*)d_in[18];
  const float* b1 = (const float*)d_in[21];
  const float* g1 = (const float*)d_in[22]; const float* be1 = (const float*)d_in[23];
  const float* W2 = (const float*)d_in[24];
  const float* pb2 = (const float*)d_in[27];
  const float* g2 = (const float*)d_in[28]; const float* be2 = (const float*)d_in[29];
  const float* Wf = (const float*)d_in[30]; const float* bfv = (const float*)d_in[31];
  const float* ln_g = (const float*)d_in[32]; const float* ln_b = (const float*)d_in[33];

  float* dout = (float*)d_out;
  char* ws = (char*)d_ws;
  u32* hbuf = (u32*)(ws + 0);
  u16* tb   = (u16*)(ws + 2129920);
  u16* Qb   = (u16*)(ws + 4227072);
  u16* Kb   = (u16*)(ws + 6324224);
  u16* Vb   = (u16*)(ws + 8421376);

  (void)hipMemsetAsync(ws, 0xFF, 2097152, stream);  // poison hbuf ring
  lstm_kernel<<<32, 256, 0, stream>>>(x, Wih_f, Whh_f, bih_f, bhh_f,
                                      Wih_b, Whh_b, bih_b, bhh_b,
                                      hbuf, tb);
  qkv_kernel<<<dim3(32, 8, 3), 256, 0, stream>>>(tb, Wq, bq, Wk, bk, Wv, bv,
                                                 Qb, Kb, Vb);
  attn_kernel<<<dim3(16, 4, 2), 256, 0, stream>>>(Qb, Kb, dout + 4096);
  tail_kernel<<<16, 512, 0, stream>>>(dout + 4096, Vb, Wo, bo,
                                      W1, b1, g1, be1, W2, pb2, g2, be2,
                                      Wf, bfv, ln_g, ln_b, dout);
}

// Round 10
// 434.736 us; speedup vs baseline: 1.5350x; 1.1606x over previous
//
#include <hip/hip_runtime.h>

// ---------------------------------------------------------------------------
// SpatioTemporalBlock: biLSTM -> temporal MHA -> (collapsed) GAT -> fusion
// B=16 S=128 F=64 H=256 HEADS=4 DH=64 AH=128 D2=512
// FP32 inputs/outputs; MFMA operands converted f32->bf16 at staging.
// GAT collapses: broadcast node features => uniform alpha => dense layers.
//
// v10 = exact revert to the verified-best v5 (433.2us total, lstm 208-212us):
//   - lstm: v1 structure + register-resident Whh/Wih B-frags + x load issued
//     before the coalesced sc1 poison poll. Fabric floor ~210us
//     (127 sequential device-scope visibility round-trips).
//   - qkv: 2-barrier LDS staging (v9's single-barrier dbuf chained the MFMA's
//     lgkmcnt wait behind next-tile global W loads -> regression; reverted).
//   - attn: v5 with coalesced float4 epilogue.
//   - tail: 256-thread v5 version (v9's 512-thr k-split was neutral/negative).
// hbuf ring [128 steps][2 dir][16 b][256 c] bf16, memset 0xFF per launch;
// h never hits the NaN bit pattern (bounded by sigmoid*tanh).
// ---------------------------------------------------------------------------

typedef unsigned short u16;
typedef unsigned int u32;
typedef __bf16 bf16x8 __attribute__((ext_vector_type(8)));
typedef float f32x4 __attribute__((ext_vector_type(4)));
typedef unsigned short ushort8v __attribute__((ext_vector_type(8)));
typedef unsigned int uint4v __attribute__((ext_vector_type(4)));

#define BN_INV_F 0.9999950000374997f
#define POISON 0xFFFFFFFFu

__device__ __forceinline__ float b2f(u16 u) {
  union { float f; unsigned int i; } v;
  v.i = ((unsigned int)u) << 16;
  return v.f;
}
__device__ __forceinline__ u16 f2b(float f) {
  union { float f; unsigned int i; } v;
  v.f = f;
  unsigned int x = v.i;
  unsigned int r = (x + 0x7FFFu + ((x >> 16) & 1u)) >> 16;
  return (u16)r;
}
__device__ __forceinline__ f32x4 mfma16(ushort8v a, ushort8v b, f32x4 c) {
  return __builtin_amdgcn_mfma_f32_16x16x32_bf16(
      __builtin_bit_cast(bf16x8, a), __builtin_bit_cast(bf16x8, b), c, 0, 0, 0);
}
__device__ __forceinline__ float sigm(float x) { return 1.f / (1.f + __expf(-x)); }
__device__ __forceinline__ float tanh_f(float x) {
  float e = __expf(2.f * x);
  return 1.f - 2.f / (e + 1.f);
}

// ---------------------------------------------------------------------------
// Kernel 1: bidirectional LSTM. grid = 32 blocks: dir = bx>>4, chunk q = bx&15.
// WG owns h-cols [q*16, q*16+16): 64 gate rows. Wave w handles gate w
// (n-rows w*16..w*16+15); per lane (quad, col16) the B-row is
// G = w*256 + q*16 + col16, fragments held in registers.
// Per step: issue x load -> poll h(t) (coalesced sc1, vmcnt(0) hides x) ->
// stage h_s + x_s -> barrier -> 10 MFMA (A from LDS, B from regs) -> z_s ->
// barrier -> per-thread gate math -> v1 coalesced publish.
// ---------------------------------------------------------------------------
__global__ __launch_bounds__(256) void lstm_kernel(
    const float* __restrict__ x,
    const float* __restrict__ Wih0, const float* __restrict__ Whh0,
    const float* __restrict__ bih0, const float* __restrict__ bhh0,
    const float* __restrict__ Wih1, const float* __restrict__ Whh1,
    const float* __restrict__ bih1, const float* __restrict__ bhh1,
    u32* __restrict__ hbuf,   // [128][2][16][128] u32 view (poisoned 0xFF)
    u16* __restrict__ tb)     // [16][128][512] bf16
{
  const int tid = threadIdx.x;
  const int bx = blockIdx.x;
  const int d = bx >> 4;
  const int q = bx & 15;
  const float* Wih = d ? Wih1 : Wih0;
  const float* Whh = d ? Whh1 : Whh0;
  const float* bih = d ? bih1 : bih0;
  const float* bhh = d ? bhh1 : bhh0;

  const int w = tid >> 6;
  const int ln = tid & 63;
  const int col16 = ln & 15;
  const int quad = ln >> 4;

  __shared__ u16 h_s[16][264];
  __shared__ u16 x_s[16][72];
  __shared__ float z_s[4][16][17];
  __shared__ float bias_s[64];

  // ---- stage weights into registers (bf16 fragments), v1 row mapping ----
  const int G = w * 256 + q * 16 + col16;   // row w*16+col16 of this chunk
  ushort8v whh_f[8];
#pragma unroll
  for (int kt = 0; kt < 8; kt++) {
    const float4* src = (const float4*)(Whh + G * 256 + kt * 32 + quad * 8);
    float4 v0 = src[0], v1 = src[1];
    ushort8v t8;
    t8[0] = f2b(v0.x); t8[1] = f2b(v0.y); t8[2] = f2b(v0.z); t8[3] = f2b(v0.w);
    t8[4] = f2b(v1.x); t8[5] = f2b(v1.y); t8[6] = f2b(v1.z); t8[7] = f2b(v1.w);
    whh_f[kt] = t8;
  }
  ushort8v wih_f[2];
#pragma unroll
  for (int kt = 0; kt < 2; kt++) {
    const float4* src = (const float4*)(Wih + G * 64 + kt * 32 + quad * 8);
    float4 v0 = src[0], v1 = src[1];
    ushort8v t8;
    t8[0] = f2b(v0.x); t8[1] = f2b(v0.y); t8[2] = f2b(v0.z); t8[3] = f2b(v0.w);
    t8[4] = f2b(v1.x); t8[5] = f2b(v1.y); t8[6] = f2b(v1.z); t8[7] = f2b(v1.w);
    wih_f[kt] = t8;
  }
  if (tid < 64) {
    int grow = ((tid >> 4) << 8) + q * 16 + (tid & 15);
    bias_s[tid] = bih[grow] + bhh[grow];
  }

  const int eb = tid >> 4;  // elementwise: batch
  const int ec = tid & 15;  // elementwise: h-col within chunk
  float c_reg = 0.f;

  for (int t = 0; t < 128; t++) {
    const int pos = d ? (127 - t) : t;

    // ---- issue x(pos) load (completion hidden under the poll) ----
    float4 xv = *(const float4*)(x + (eb * 128 + pos) * 64 + ec * 4);

    if (t > 0) {
      // poll full h(t): 8 u32 words per thread via 2 coalesced sc1 x4 loads
      const u32* hw = hbuf + (t * 2 + d) * 2048 + tid * 8;
      uint4v a, b;
      for (;;) {
        asm volatile(
            "global_load_dwordx4 %0, %2, off sc1\n\t"
            "global_load_dwordx4 %1, %3, off sc1\n\t"
            "s_waitcnt vmcnt(0)"
            : "=v"(a), "=v"(b)
            : "v"(hw), "v"(hw + 4)
            : "memory");
        bool ok = (a.x != POISON) & (a.y != POISON) & (a.z != POISON) &
                  (a.w != POISON) & (b.x != POISON) & (b.y != POISON) &
                  (b.z != POISON) & (b.w != POISON);
        if (ok) break;
      }
      int b_ = tid >> 4, c0 = (tid & 15) * 16;
      *(u32*)&h_s[b_][c0 + 0] = a.x;
      *(u32*)&h_s[b_][c0 + 2] = a.y;
      *(u32*)&h_s[b_][c0 + 4] = a.z;
      *(u32*)&h_s[b_][c0 + 6] = a.w;
      *(u32*)&h_s[b_][c0 + 8] = b.x;
      *(u32*)&h_s[b_][c0 + 10] = b.y;
      *(u32*)&h_s[b_][c0 + 12] = b.z;
      *(u32*)&h_s[b_][c0 + 14] = b.w;
    }
    // stage x(pos) -> bf16 LDS (data already in flight / arrived)
    {
      int f0 = ec * 4;
      x_s[eb][f0 + 0] = f2b(xv.x);
      x_s[eb][f0 + 1] = f2b(xv.y);
      x_s[eb][f0 + 2] = f2b(xv.z);
      x_s[eb][f0 + 3] = f2b(xv.w);
    }
    __syncthreads();

    f32x4 acc = {0.f, 0.f, 0.f, 0.f};
#pragma unroll
    for (int kt = 0; kt < 2; kt++) {
      ushort8v av = *(const ushort8v*)&x_s[col16][kt * 32 + quad * 8];
      acc = mfma16(av, wih_f[kt], acc);
    }
    if (t > 0) {
#pragma unroll
      for (int kt = 0; kt < 8; kt++) {
        ushort8v av = *(const ushort8v*)&h_s[col16][kt * 32 + quad * 8];
        acc = mfma16(av, whh_f[kt], acc);
      }
    }
#pragma unroll
    for (int reg = 0; reg < 4; reg++)
      z_s[w][quad * 4 + reg][col16] = acc[reg];
    __syncthreads();

    // gates: torch order i, f, g, o (f32) — one element per thread
    float zi = z_s[0][eb][ec] + bias_s[ec];
    float zf = z_s[1][eb][ec] + bias_s[16 + ec];
    float zg = z_s[2][eb][ec] + bias_s[32 + ec];
    float zo = z_s[3][eb][ec] + bias_s[48 + ec];
    float si = sigm(zi), sf = sigm(zf), so = sigm(zo);
    float tg = tanh_f(zg);
    c_reg = sf * c_reg + si * tg;
    float hv = so * tanh_f(c_reg);
    u32 my = (u32)f2b(hv);
    u32 hi = __shfl_down((int)my, 1);  // partner col (ec+1), same wave
    if ((ec & 1) == 0) {
      u32 word = my | (hi << 16);
      *(u32*)&tb[(eb * 128 + pos) * 512 + d * 256 + q * 16 + ec] = word;
      if (t < 127) {
        u32* dst = hbuf + ((t + 1) * 2 + d) * 2048 + eb * 128 + (q * 16 + ec) / 2;
        __hip_atomic_store(dst, word, __ATOMIC_RELAXED,
                           __HIP_MEMORY_SCOPE_AGENT);
      }
    }
    // no extra barrier: next-iter writes touch x_s/h_s only, whose reads all
    // completed before the z_s barrier above.
  }
}

// ---------------------------------------------------------------------------
// Kernel 2: QKV projection.  out = t @ W^T + bias, M=2048 N=512 K=512.
// grid = (32 Mtiles, 8 Ntiles, 3 which). Q,K,V stored bf16.
// ---------------------------------------------------------------------------
__global__ __launch_bounds__(256) void qkv_kernel(
    const u16* __restrict__ tb,
    const float* __restrict__ Wq, const float* __restrict__ bq,
    const float* __restrict__ Wk, const float* __restrict__ bk,
    const float* __restrict__ Wv, const float* __restrict__ bv,
    u16* __restrict__ Qb, u16* __restrict__ Kb, u16* __restrict__ Vb)
{
  const int tid = threadIdx.x;
  const int bxm = blockIdx.x, byn = blockIdx.y, bz = blockIdx.z;
  const float* W = (bz == 0) ? Wq : ((bz == 1) ? Wk : Wv);
  const float* bias = (bz == 0) ? bq : ((bz == 1) ? bk : bv);
  u16* outp = (bz == 0) ? Qb : ((bz == 1) ? Kb : Vb);

  __shared__ u16 a_s[64][40];
  __shared__ u16 b_s[64][40];
  const int w = tid >> 6, ln = tid & 63, col16 = ln & 15, quad = ln >> 4;

  f32x4 acc[4];
#pragma unroll
  for (int n = 0; n < 4; n++) acc[n] = (f32x4){0.f, 0.f, 0.f, 0.f};

  for (int kt = 0; kt < 16; kt++) {
    int r = tid >> 2, seg = tid & 3;
    *(ushort8v*)&a_s[r][seg * 8] =
        *(const ushort8v*)(tb + (bxm * 64 + r) * 512 + kt * 32 + seg * 8);
    const float4* wsrc = (const float4*)(W + (byn * 64 + r) * 512 + kt * 32 + seg * 8);
    float4 w0 = wsrc[0], w1 = wsrc[1];
    b_s[r][seg * 8 + 0] = f2b(w0.x);
    b_s[r][seg * 8 + 1] = f2b(w0.y);
    b_s[r][seg * 8 + 2] = f2b(w0.z);
    b_s[r][seg * 8 + 3] = f2b(w0.w);
    b_s[r][seg * 8 + 4] = f2b(w1.x);
    b_s[r][seg * 8 + 5] = f2b(w1.y);
    b_s[r][seg * 8 + 6] = f2b(w1.z);
    b_s[r][seg * 8 + 7] = f2b(w1.w);
    __syncthreads();
    ushort8v av = *(const ushort8v*)&a_s[w * 16 + col16][quad * 8];
#pragma unroll
    for (int n = 0; n < 4; n++) {
      ushort8v bvv = *(const ushort8v*)&b_s[n * 16 + col16][quad * 8];
      acc[n] = mfma16(av, bvv, acc[n]);
    }
    __syncthreads();
  }
#pragma unroll
  for (int n = 0; n < 4; n++) {
    float bs = bias[byn * 64 + n * 16 + col16];
#pragma unroll
    for (int reg = 0; reg < 4; reg++) {
      int row = bxm * 64 + w * 16 + quad * 4 + reg;
      outp[row * 512 + byn * 64 + n * 16 + col16] = f2b(acc[n][reg] + bs);
    }
  }
}

// ---------------------------------------------------------------------------
// Kernel 3: scores + softmax -> attn (d_out, f32). grid = (16 b, 4 h, 2 qhalf).
// Epilogue: per-row inv staged in LDS, cooperative coalesced float4 stores.
// ---------------------------------------------------------------------------
__global__ __launch_bounds__(256) void attn_kernel(
    const u16* __restrict__ Qb, const u16* __restrict__ Kb,
    float* __restrict__ attn_out)
{
  const int b = blockIdx.x, h = blockIdx.y, half = blockIdx.z;
  const int tid = threadIdx.x;
  __shared__ __align__(16) char smem[52224];
  __shared__ float inv_s[64];
  u16 (*q_s)[136] = (u16(*)[136])smem;
  u16 (*k_s)[136] = (u16(*)[136])(smem + 17408);
  float (*sc)[132] = (float(*)[132])smem;  // reused after MFMA

  const int w = tid >> 6, ln = tid & 63, col16 = ln & 15, quad = ln >> 4;
  {
    int r = tid >> 2, seg = tid & 3;
    const u16* src = Qb + (b * 128 + half * 64 + r) * 512 + h * 128 + seg * 32;
#pragma unroll
    for (int i = 0; i < 4; i++)
      *(ushort8v*)&q_s[r][seg * 32 + i * 8] = *(const ushort8v*)(src + i * 8);
    int r2 = tid >> 1, sg = tid & 1;
    const u16* src2 = Kb + (b * 128 + r2) * 512 + h * 128 + sg * 64;
#pragma unroll
    for (int i = 0; i < 8; i++)
      *(ushort8v*)&k_s[r2][sg * 64 + i * 8] = *(const ushort8v*)(src2 + i * 8);
  }
  __syncthreads();

  f32x4 acc[8];
#pragma unroll
  for (int n = 0; n < 8; n++) acc[n] = (f32x4){0.f, 0.f, 0.f, 0.f};
#pragma unroll
  for (int kd = 0; kd < 4; kd++) {
    ushort8v av = *(const ushort8v*)&q_s[w * 16 + col16][kd * 32 + quad * 8];
#pragma unroll
    for (int n = 0; n < 8; n++) {
      ushort8v bvv = *(const ushort8v*)&k_s[n * 16 + col16][kd * 32 + quad * 8];
      acc[n] = mfma16(av, bvv, acc[n]);
    }
  }
  __syncthreads();  // done with q_s/k_s before overwriting with sc
  const float scale = 0.08838834764831845f;  // 1/sqrt(128)
#pragma unroll
  for (int n = 0; n < 8; n++)
#pragma unroll
    for (int reg = 0; reg < 4; reg++)
      sc[w * 16 + quad * 4 + reg][n * 16 + col16] = acc[n][reg] * scale;
  __syncthreads();

  const int row = tid >> 2, p = tid & 3;
  float m = -1e30f;
  for (int c0 = 0; c0 < 32; c0++) m = fmaxf(m, sc[row][p * 32 + c0]);
  m = fmaxf(m, __shfl_xor(m, 1));
  m = fmaxf(m, __shfl_xor(m, 2));
  float s = 0.f;
  for (int c0 = 0; c0 < 32; c0++) {
    float e = __expf(sc[row][p * 32 + c0] - m);
    sc[row][p * 32 + c0] = e;
    s += e;
  }
  s += __shfl_xor(s, 1);
  s += __shfl_xor(s, 2);
  if (p == 0) inv_s[row] = 1.f / s;
  __syncthreads();

  // cooperative coalesced store: 64 rows x 128 f32
  float* obase = attn_out + (size_t)((b * 4 + h) * 128 + half * 64) * 128;
#pragma unroll
  for (int it = 0; it < 8; it++) {
    int idx = tid + it * 256;     // 0..2047
    int r = idx >> 5;             // row 0..63
    int c4 = idx & 31;            // float4 index 0..31
    float4 ev = *(float4*)&sc[r][c4 * 4];
    float iv = inv_s[r];
    float4 ov = {ev.x * iv, ev.y * iv, ev.z * iv, ev.w * iv};
    *(float4*)&obase[r * 128 + c4 * 4] = ov;
  }
}

// ---------------------------------------------------------------------------
// Kernel 4 (merged aolast+fuse): ao (q=127 only), last = ao@Wo^T+bo,
// collapsed GAT (2 dense layers), fusion Linear + LayerNorm + ReLU.
// grid = 16 (batch), 256 threads.
// ---------------------------------------------------------------------------
__global__ __launch_bounds__(256) void tail_kernel(
    const float* __restrict__ attn, const u16* __restrict__ Vb,
    const float* __restrict__ Wo, const float* __restrict__ bo,
    const float* __restrict__ W1, const float* __restrict__ b1,
    const float* __restrict__ g1, const float* __restrict__ be1,
    const float* __restrict__ W2, const float* __restrict__ pb2,
    const float* __restrict__ g2, const float* __restrict__ be2,
    const float* __restrict__ Wf, const float* __restrict__ bfv,
    const float* __restrict__ ln_g, const float* __restrict__ ln_b,
    float* __restrict__ dout)
{
  const int b = blockIdx.x, tid = threadIdx.x;
  __shared__ float arow[4][128];
  __shared__ float ao_s[512];
  __shared__ float last_s[512];
  __shared__ float h_s2[256];
  __shared__ float red_s[4];

  // ---- ao row (q=127) ----
#pragma unroll
  for (int e = 0; e < 2; e++) {
    int idx = tid + e * 256;
    int h = idx >> 7, k = idx & 127;
    arow[h][k] = attn[((b * 4 + h) * 128 + 127) * 128 + k];
  }
  __syncthreads();
#pragma unroll
  for (int pass = 0; pass < 2; pass++) {
    int d2 = tid + pass * 256;
    int hh = d2 >> 7;
    float acc = 0.f;
    for (int k = 0; k < 128; k++)
      acc += arow[hh][k] * b2f(Vb[(b * 128 + k) * 512 + d2]);
    ao_s[d2] = acc;
  }
  __syncthreads();
  // ---- last = ao @ Wo^T + bo ----
#pragma unroll
  for (int pass = 0; pass < 2; pass++) {
    int j = tid + pass * 256;
    float acc = bo[j];
    const float4* Wo4 = (const float4*)(Wo + j * 512);
    for (int k4 = 0; k4 < 128; k4++) {
      float4 wv = Wo4[k4];
      acc += ao_s[k4 * 4 + 0] * wv.x + ao_s[k4 * 4 + 1] * wv.y +
             ao_s[k4 * 4 + 2] * wv.z + ao_s[k4 * 4 + 3] * wv.w;
    }
    last_s[j] = acc;
  }
  __syncthreads();

  // ---- collapsed GAT layer 1 ----
  const int j = tid;
  float acc = 0.f;
  for (int k = 0; k < 512; k++) acc += last_s[k] * W1[k * 256 + j];
  float u = (acc + b1[j]) * BN_INV_F * g1[j] + be1[j];
  float h1 = u > 0.f ? u : expm1f(u);
  h_s2[j] = h1;
  __syncthreads();

  // ---- collapsed GAT layer 2 ----
  float acc2 = 0.f;
  for (int k = 0; k < 256; k++) acc2 += h_s2[k] * W2[k * 256 + j];
  float u2 = (acc2 + pb2[j]) * BN_INV_F * g2[j] + be2[j];
  float sp = u2 > 0.f ? u2 : expm1f(u2);
  __syncthreads();
  h_s2[j] = sp;
  __syncthreads();

  // ---- fusion Linear ----
  float f = bfv[j];
  const float4* Wf4 = (const float4*)(Wf + j * 768);
  for (int k4 = 0; k4 < 128; k4++) {
    float4 wv = Wf4[k4];
    f += last_s[k4 * 4 + 0] * wv.x + last_s[k4 * 4 + 1] * wv.y +
         last_s[k4 * 4 + 2] * wv.z + last_s[k4 * 4 + 3] * wv.w;
  }
  for (int k4 = 0; k4 < 64; k4++) {
    float4 wv = Wf4[128 + k4];
    f += h_s2[k4 * 4 + 0] * wv.x + h_s2[k4 * 4 + 1] * wv.y +
         h_s2[k4 * 4 + 2] * wv.z + h_s2[k4 * 4 + 3] * wv.w;
  }

  // ---- LayerNorm + ReLU ----
  float v = f;
#pragma unroll
  for (int o = 32; o > 0; o >>= 1) v += __shfl_xor(v, o);
  if ((tid & 63) == 0) red_s[tid >> 6] = v;
  __syncthreads();
  float mu = (red_s[0] + red_s[1] + red_s[2] + red_s[3]) * (1.f / 256.f);
  float dv = f - mu;
  float vv = dv * dv;
#pragma unroll
  for (int o = 32; o > 0; o >>= 1) vv += __shfl_xor(vv, o);
  __syncthreads();
  if ((tid & 63) == 0) red_s[tid >> 6] = vv;
  __syncthreads();
  float var = (red_s[0] + red_s[1] + red_s[2] + red_s[3]) * (1.f / 256.f);
  float y = dv * rsqrtf(var + 1e-5f) * ln_g[j] + ln_b[j];
  dout[b * 256 + j] = fmaxf(y, 0.f);
}

// ---------------------------------------------------------------------------
// ws layout (bytes):
//   0         hbuf  [128][2][16][256] bf16  2097152  (memset 0xFF each call)
//   2129920   tb    [16][128][512] bf16     2097152
//   4227072   Q     [2048][512] bf16        2097152
//   6324224   K     [2048][512] bf16        2097152
//   8421376   V     [2048][512] bf16        2097152  -> total 10518528 bytes
// ---------------------------------------------------------------------------
extern "C" void kernel_launch(void* const* d_in, const int* in_sizes, int n_in,
                              void* d_out, int out_size, void* d_ws, size_t ws_size,
                              hipStream_t stream) {
  (void)in_sizes; (void)n_in; (void)out_size; (void)ws_size;
  const float* x     = (const float*)d_in[0];
  const float* Wih_f = (const float*)d_in[2];
  const float* Whh_f = (const float*)d_in[3];
  const float* bih_f = (const float*)d_in[4];
  const float* bhh_f = (const float*)d_in[5];
  const float* Wih_b = (const float*)d_in[6];
  const float* Whh_b = (const float*)d_in[7];
  const float* bih_b = (const float*)d_in[8];
  const float* bhh_b = (const float*)d_in[9];
  const float* Wq = (const float*)d_in[10]; const float* bq = (const float*)d_in[11];
  const float* Wk = (const float*)d_in[12]; const float* bk = (const float*)d_in[13];
  const float* Wv = (const float*)d_in[14]; const float* bv = (const float*)d_in[15];
  const float* Wo = (const float*)d_in[16]; const float* bo = (const float*)d_in[17];
  const float* W1 = (const float*)d_in[18];
  const float* b1 = (const float*)d_in[21];
  const float* g1 = (const float*)d_in[22]; const float* be1 = (const float*)d_in[23];
  const float* W2 = (const float*)d_in[24];
  const float* pb2 = (const float*)d_in[27];
  const float* g2 = (const float*)d_in[28]; const float* be2 = (const float*)d_in[29];
  const float* Wf = (const float*)d_in[30]; const float* bfv = (const float*)d_in[31];
  const float* ln_g = (const float*)d_in[32]; const float* ln_b = (const float*)d_in[33];

  float* dout = (float*)d_out;
  char* ws = (char*)d_ws;
  u32* hbuf = (u32*)(ws + 0);
  u16* tb   = (u16*)(ws + 2129920);
  u16* Qb   = (u16*)(ws + 4227072);
  u16* Kb   = (u16*)(ws + 6324224);
  u16* Vb   = (u16*)(ws + 8421376);

  (void)hipMemsetAsync(ws, 0xFF, 2097152, stream);  // poison hbuf ring
  lstm_kernel<<<32, 256, 0, stream>>>(x, Wih_f, Whh_f, bih_f, bhh_f,
                                      Wih_b, Whh_b, bih_b, bhh_b,
                                      hbuf, tb);
  qkv_kernel<<<dim3(32, 8, 3), 256, 0, stream>>>(tb, Wq, bq, Wk, bk, Wv, bv,
                                                 Qb, Kb, Vb);
  attn_kernel<<<dim3(16, 4, 2), 256, 0, stream>>>(Qb, Kb, dout + 4096);
  tail_kernel<<<16, 256, 0, stream>>>(dout + 4096, Vb, Wo, bo,
                                      W1, b1, g1, be1, W2, pb2, g2, be2,
                                      Wf, bfv, ln_g, ln_b, dout);
}